// Round 20
// baseline (774.903 us; speedup 1.0000x reference)
//
#include <hip/hip_runtime.h>
#include <hip/hip_bf16.h>
#include <cmath>

// ---------------- constants ----------------
#define Bn     32
#define SYc    512
#define SXc    1024
#define Fdim   512
#define INdim  256
#define Hdim   512
#define EMBdim 256
#define Vdim   128
#define NYc    16384
#define NXc    32768
#define Ec     49152
#define CBc    4
#define NCHUNK (Bn / CBc)
#define YRc    (CBc * SYc)
#define XRc    (CBc * SXc)

typedef float f4v __attribute__((ext_vector_type(4)));
typedef short s8v __attribute__((ext_vector_type(8)));
typedef short s4v __attribute__((ext_vector_type(4)));
typedef __hip_bfloat16 bf16;

__device__ __forceinline__ float ldf(const float* p) { return *p; }
__device__ __forceinline__ float ldf(const bf16* p) { return __bfloat162float(*p); }
__device__ __forceinline__ void stf(float* p, float v) { *p = v; }
__device__ __forceinline__ void stf(bf16* p, float v) { *p = __float2bfloat16(v); }
__device__ __forceinline__ short f2b(float x) {
    bf16 h = __float2bfloat16(x);
    return *reinterpret_cast<const short*>(&h);
}
__device__ __forceinline__ float b2f(short s) {
    bf16 h = *reinterpret_cast<const bf16*>(&s);
    return __bfloat162float(h);
}

// async global->LDS, 16B per lane; dst = base + lane*16 (wave-uniform base)
__device__ __forceinline__ void gload16(const void* g, void* l) {
    __builtin_amdgcn_global_load_lds((const __attribute__((address_space(1))) void*)g,
                                     (__attribute__((address_space(3))) void*)l, 16, 0, 0);
}

// ================= MFMA bf16 GEMM =================
enum { EP_F32 = 0, EP_F32ACC, EP_BF16, EP_RELUB, EP_BIAS };

template <typename TA, int EP>
__global__ __launch_bounds__(256) void mgemm_k(
    const TA* __restrict__ A, const bf16* __restrict__ BT,
    float* __restrict__ Cf, bf16* __restrict__ Cb,
    const float* __restrict__ H, const float* __restrict__ bias,
    int M, int N, int K, int ldA, int ldB,
    long sA, long sB, long sC)
{
    __shared__ s8v As[512];   // unit u = row*4 + slot; slot = (kp + (row>>1))&3
    __shared__ s8v Bs[512];
    // XCD-aware bijective swizzle (m204)
    const int nwg = gridDim.x * gridDim.y;
    const int flat = blockIdx.y * gridDim.x + blockIdx.x;
    const int qd = nwg >> 3, rm = nwg & 7;
    const int xcd = flat & 7, base = flat >> 3;
    const int wgid = (xcd < rm ? xcd * (qd + 1) : rm * (qd + 1) + (xcd - rm) * qd) + base;
    const int bx = wgid % gridDim.x, by = wgid / gridDim.x;

    const int tid = threadIdx.x;
    const int l = tid & 63, w = tid >> 6;
    const int wr = w >> 1, wc = w & 1;
    const long bm = (long)by * 128, bn = (long)bx * 128;
    const int z = blockIdx.z;
    const TA* Ab = A + (long)z * sA;
    const bf16* Bb = BT + (long)z * sB;
    const int l15 = l & 15, kq = l >> 4;

    f4v acc[4][4];
#pragma unroll
    for (int i = 0; i < 4; ++i)
#pragma unroll
        for (int j = 0; j < 4; ++j) acc[i][j] = f4v{0.f, 0.f, 0.f, 0.f};

    for (int k0 = 0; k0 < K; k0 += 32) {
        if constexpr (sizeof(TA) == 2) {
#pragma unroll
            for (int i = 0; i < 2; ++i) {
                const int u = w * 128 + i * 64 + l;
                const int row = u >> 2, slot = u & 3;
                const int kp = (slot - (row >> 1)) & 3;
                gload16((const bf16*)Ab + (bm + row) * (long)ldA + k0 + kp * 8,
                        &As[w * 128 + i * 64]);
                gload16(Bb + (bn + row) * (long)ldB + k0 + kp * 8,
                        &Bs[w * 128 + i * 64]);
            }
        } else {
#pragma unroll
            for (int j = 0; j < 2; ++j) {
                const int id = tid * 2 + j;
                const int row = id >> 2, kp = id & 3;
                const int slot = (kp + (row >> 1)) & 3;
                const float* ap = (const float*)Ab + (bm + row) * (long)ldA + k0 + kp * 8;
                f4v v0 = *(const f4v*)ap, v1 = *(const f4v*)(ap + 4);
                s8v t;
                t[0] = f2b(v0.x); t[1] = f2b(v0.y); t[2] = f2b(v0.z); t[3] = f2b(v0.w);
                t[4] = f2b(v1.x); t[5] = f2b(v1.y); t[6] = f2b(v1.z); t[7] = f2b(v1.w);
                As[row * 4 + slot] = t;
            }
#pragma unroll
            for (int i = 0; i < 2; ++i) {
                const int u = w * 128 + i * 64 + l;
                const int row = u >> 2, slot = u & 3;
                const int kp = (slot - (row >> 1)) & 3;
                gload16(Bb + (bn + row) * (long)ldB + k0 + kp * 8,
                        &Bs[w * 128 + i * 64]);
            }
        }
        __syncthreads();
        s8v af[4], bfr[4];
#pragma unroll
        for (int f = 0; f < 4; ++f) {
            const int ar = wr * 64 + f * 16 + l15;
            af[f] = As[ar * 4 + ((kq + (ar >> 1)) & 3)];
            const int br = wc * 64 + f * 16 + l15;
            bfr[f] = Bs[br * 4 + ((kq + (br >> 1)) & 3)];
        }
#pragma unroll
        for (int i = 0; i < 4; ++i)
#pragma unroll
            for (int j = 0; j < 4; ++j)
                acc[i][j] = __builtin_amdgcn_mfma_f32_16x16x32_bf16(af[i], bfr[j], acc[i][j], 0, 0, 0);
        __syncthreads();
    }

#pragma unroll
    for (int i = 0; i < 4; ++i)
#pragma unroll
        for (int j = 0; j < 4; ++j)
#pragma unroll
            for (int r = 0; r < 4; ++r) {
                const long row = bm + wr * 64 + i * 16 + kq * 4 + r;
                const long col = bn + wc * 64 + j * 16 + l15;
                const long idx = (long)z * sC + row * N + col;
                float v = acc[i][j][r];
                if constexpr (EP == EP_F32) Cf[idx] = v;
                else if constexpr (EP == EP_F32ACC) Cf[idx] += v;
                else if constexpr (EP == EP_BF16) Cb[idx] = __float2bfloat16(v);
                else if constexpr (EP == EP_BIAS) Cf[idx] = v + bias[col];
                else {  // EP_RELUB
                    v += __bfloat162float(((const bf16*)H)[idx]);
                    v = fmaxf(v, 0.f);
                    Cb[idx] = __float2bfloat16(v);
                    if (Cf) Cf[idx] = v;
                }
            }
}

// ================= batched weight transpose (ALL weights, one launch) ==========
#define NWENT 27
struct WArg {
    const float* s[NWENT];
    long d[NWENT];
    int K[NWENT], N[NWENT];
    int t0[NWENT + 1];
};

__global__ __launch_bounds__(256) void wtrall_k(WArg a, bf16* __restrict__ wbt)
{
    __shared__ float T[32][33];
    int b = blockIdx.x;
    int e = 0;
    while (b >= a.t0[e + 1]) ++e;
    const int lt = b - a.t0[e];
    const int K = a.K[e], N = a.N[e];
    const int tx = N >> 5;
    const int n0 = (lt % tx) * 32, k0 = (lt / tx) * 32;
    const float* src = a.s[e];
    bf16* dst = wbt + a.d[e];
    const int t = threadIdx.x;
    const int kr = t >> 3, nc = (t & 7) * 4;
    f4v v = *(const f4v*)(src + (long)(k0 + kr) * N + n0 + nc);
    T[kr][nc] = v.x; T[kr][nc + 1] = v.y; T[kr][nc + 2] = v.z; T[kr][nc + 3] = v.w;
    __syncthreads();
    const int nr = t >> 3, kc = (t & 7) * 4;
    bf16* dp = dst + (long)(n0 + nr) * K + k0 + kc;
    dp[0] = __float2bfloat16(T[kc][nr]);
    dp[1] = __float2bfloat16(T[kc + 1][nr]);
    dp[2] = __float2bfloat16(T[kc + 2][nr]);
    dp[3] = __float2bfloat16(T[kc + 3][nr]);
}

// ================= batched f32->bf16 convert (8 tensors, one launch) ==========
#define NCENT 8
struct CvArg {
    const float* s[NCENT];
    bf16* d[NCENT];
    long t0[NCENT + 1];   // prefix in 8-elem groups
};

__global__ void cvall_k(CvArg a)
{
    long idx = (long)blockIdx.x * blockDim.x + threadIdx.x;
    if (idx >= a.t0[NCENT]) return;
    int e = 0;
    while (idx >= a.t0[e + 1]) ++e;
    const long g = idx - a.t0[e];
    const f4v v0 = ((const f4v*)a.s[e])[g * 2], v1 = ((const f4v*)a.s[e])[g * 2 + 1];
    s8v t;
    t[0] = f2b(v0.x); t[1] = f2b(v0.y); t[2] = f2b(v0.z); t[3] = f2b(v0.w);
    t[4] = f2b(v1.x); t[5] = f2b(v1.y); t[6] = f2b(v1.z); t[7] = f2b(v1.w);
    ((s8v*)a.d[e])[g] = t;
}

// v transpose: bf16 [NXc][ldIn] (cols [0,C)) -> per-batch [C][SXc]
__global__ __launch_bounds__(256) void vtr_k(const bf16* __restrict__ in,
                                             bf16* __restrict__ outp, int C, int ldIn)
{
    __shared__ short T[64][72];
    const int r0 = blockIdx.x * 64, c0 = blockIdx.y * 64;
    const int t = threadIdx.x;
    const int rr = t >> 2, cc = (t & 3) * 16;
    const bf16* ip = in + (long)(r0 + rr) * ldIn + c0 + cc;
    *(s8v*)&T[rr][cc] = *(const s8v*)ip;
    *(s8v*)&T[rr][cc + 8] = *(const s8v*)(ip + 8);
    __syncthreads();
    const int cr = t >> 2, rs = (t & 3) * 16;
    const int b = r0 >> 10, s0 = r0 & 1023;
    bf16* dp = outp + ((long)b * C + (c0 + cr)) * SXc + s0 + rs;
    s8v o0, o1;
#pragma unroll
    for (int i = 0; i < 8; ++i) { o0[i] = T[rs + i][cr]; o1[i] = T[rs + 8 + i][cr]; }
    *(s8v*)dp = o0;
    *(s8v*)(dp + 8) = o1;
}

// ================= CSR build =================
__global__ void zeroi_k(int* __restrict__ p, int n)
{
    int i = blockIdx.x * blockDim.x + threadIdx.x;
    if (i < n) p[i] = 0;
}

__global__ void csr_cnt_k(const int* __restrict__ tgt, int* __restrict__ cnt)
{
    int e = blockIdx.x * blockDim.x + threadIdx.x;
    if (e < Ec) atomicAdd(&cnt[tgt[e] & (NYc - 1)], 1);
}

__global__ __launch_bounds__(256) void csr_scan_k(const int* __restrict__ cnt,
                                                  int* __restrict__ ptr,
                                                  int* __restrict__ pfill)
{
    __shared__ int ps[256];
    const int t = threadIdx.x;
    const int base = t * 64;
    int sum = 0;
    for (int i = 0; i < 64; ++i) sum += cnt[base + i];
    ps[t] = sum;
    __syncthreads();
    for (int off = 1; off < 256; off <<= 1) {
        int v = (t >= off) ? ps[t - off] : 0;
        __syncthreads();
        ps[t] += v;
        __syncthreads();
    }
    int run = (t == 0) ? 0 : ps[t - 1];
    for (int i = 0; i < 64; ++i) {
        ptr[base + i] = run;
        pfill[base + i] = run;
        run += cnt[base + i];
    }
    if (t == 255) ptr[NYc] = run;
}

__global__ void csr_fill_k(const int* __restrict__ src, const int* __restrict__ tgt,
                           const int* __restrict__ et, int* __restrict__ pfill,
                           int* __restrict__ srcrow)
{
    int e = blockIdx.x * blockDim.x + threadIdx.x;
    if (e >= Ec) return;
    int t = tgt[e] & (NYc - 1);
    int pos = atomicAdd(&pfill[t], 1);
    srcrow[pos] = ((src[e] & (NYc - 1)) << 2) | (et[e] & 3);
}

// h(bf16) = Z5.self[zrow(t)] + sum_{edges->t} Z5.rel[et][zrow(src)] (+ ib[irow(t)]).
__global__ __launch_bounds__(256) void gather_k(const bf16* __restrict__ Z5,
                                                const int* __restrict__ ptr,
                                                const int* __restrict__ srcrow,
                                                const bf16* __restrict__ ib,
                                                const int* __restrict__ imap,
                                                const int* __restrict__ zmap,
                                                bf16* __restrict__ hbf,
                                                int O, int sh3 /*log2(O/8)*/)
{
    int idx = blockIdx.x * blockDim.x + threadIdx.x;
    int t = idx >> sh3;
    int c8 = (idx & ((1 << sh3) - 1)) * 8;
    const long fiveO = 5L * O;
    float s[8];
    {
        const int zt = zmap ? (zmap[t] & (Vdim - 1)) : t;
        const s8v v = *(const s8v*)(Z5 + (long)zt * fiveO + c8);
#pragma unroll
        for (int j = 0; j < 8; ++j) s[j] = b2f(v[j]);
    }
    if (ib) {
        const int it = imap ? (imap[t] & (Vdim - 1)) : t;
        const s8v v = *(const s8v*)(ib + (long)it * O + c8);
#pragma unroll
        for (int j = 0; j < 8; ++j) s[j] += b2f(v[j]);
    }
    const int beg = ptr[t], end = ptr[t + 1];
    for (int i = beg; i < end; ++i) {
        const int sr = srcrow[i];
        int srow = sr >> 2;
        const int et = sr & 3;
        if (zmap) srow = zmap[srow] & (Vdim - 1);
        const s8v v = *(const s8v*)(Z5 + (long)srow * fiveO + (long)(1 + et) * O + c8);
#pragma unroll
        for (int j = 0; j < 8; ++j) s[j] += b2f(v[j]);
    }
    s8v hv;
#pragma unroll
    for (int j = 0; j < 8; ++j) hv[j] = f2b(s[j]);
    *(s8v*)(hbf + (long)t * O + c8) = hv;
}

// ================= shared small kernels =================
__global__ void embed_k(const float* __restrict__ embed, const int* __restrict__ ids,
                        bf16* __restrict__ y, int n)
{
    int idx = blockIdx.x * blockDim.x + threadIdx.x;
    if (idx >= n) return;
    int row = idx >> 6, q = idx & 63;
    int id = ids[row] & (Vdim - 1);
    f4v v = ((const f4v*)embed)[(long)id * 64 + q];
    bf16* yp = y + (long)row * 256 + q * 4;
    yp[0] = __float2bfloat16(v.x); yp[1] = __float2bfloat16(v.y);
    yp[2] = __float2bfloat16(v.z); yp[3] = __float2bfloat16(v.w);
}

// legacy scatter (fallback path)
__global__ void scatter_k(const bf16* __restrict__ y, const int* __restrict__ src,
                          const int* __restrict__ tgt, const int* __restrict__ et,
                          float* __restrict__ agg, int E, int sh, int r)
{
    int idx = blockIdx.x * blockDim.x + threadIdx.x;
    if (idx >= (E << sh)) return;
    int e = idx >> sh;
    if ((et[e] & 3) != r) return;
    int c = (idx & ((1 << sh) - 1)) * 4;
    int D = 4 << sh;
    int s = src[e] & (NYc - 1);
    int t = tgt[e] & (NYc - 1);
    const bf16* yp = y + (long)s * D + c;
    float* ap = agg + (long)t * D + c;
    atomicAdd(ap + 0, __bfloat162float(yp[0]));
    atomicAdd(ap + 1, __bfloat162float(yp[1]));
    atomicAdd(ap + 2, __bfloat162float(yp[2]));
    atomicAdd(ap + 3, __bfloat162float(yp[3]));
}

__global__ void zero_k(float* __restrict__ p, long n4)
{
    long i = (long)blockIdx.x * blockDim.x + threadIdx.x;
    const long stride = (long)gridDim.x * blockDim.x;
    for (; i < n4; i += stride) ((f4v*)p)[i] = f4v{0.f, 0.f, 0.f, 0.f};
}

// softmax: wave-per-row; bf16 scores -> f32 alpha + bf16 mirror
__global__ __launch_bounds__(256) void softmax3_k(const bf16* __restrict__ sin,
                                                  float* __restrict__ aout,
                                                  bf16* __restrict__ amir, float scale)
{
    const int wid = threadIdx.x >> 6;
    const int l = threadIdx.x & 63;
    const long row = (long)blockIdx.x * 4 + wid;
    const bf16* sp = sin + row * SXc + l * 16;
    float v[16];
    {
        const s8v a0 = *(const s8v*)sp;
        const s8v a1 = *(const s8v*)(sp + 8);
#pragma unroll
        for (int i = 0; i < 8; ++i) { v[i] = b2f(a0[i]) * scale; v[8 + i] = b2f(a1[i]) * scale; }
    }
    float m = v[0];
#pragma unroll
    for (int i = 1; i < 16; ++i) m = fmaxf(m, v[i]);
    for (int off = 32; off > 0; off >>= 1) m = fmaxf(m, __shfl_xor(m, off));
    float sum = 0.f;
#pragma unroll
    for (int i = 0; i < 16; ++i) { v[i] = __expf(v[i] - m); sum += v[i]; }
    for (int off = 32; off > 0; off >>= 1) sum += __shfl_xor(sum, off);
    const float inv = 1.0f / sum;
    float* ap = aout + row * SXc + l * 16;
    bf16* mp = amir + row * SXc + l * 16;
    f4v o0, o1, o2, o3;
    s8v m0, m1;
#pragma unroll
    for (int i = 0; i < 4; ++i) {
        o0[i] = v[i] * inv; o1[i] = v[4 + i] * inv;
        o2[i] = v[8 + i] * inv; o3[i] = v[12 + i] * inv;
    }
#pragma unroll
    for (int i = 0; i < 8; ++i) { m0[i] = f2b(v[i] * inv); m1[i] = f2b(v[8 + i] * inv); }
    ((f4v*)ap)[0] = o0; ((f4v*)ap)[1] = o1; ((f4v*)ap)[2] = o2; ((f4v*)ap)[3] = o3;
    *(s8v*)mp = m0; *(s8v*)(mp + 8) = m1;
}

// softmax in-place f32 (fallback path)
__global__ __launch_bounds__(256) void softmax2_k(float* __restrict__ s,
                                                  bf16* __restrict__ ab, float scale)
{
    __shared__ float red[256];
    float* sp = s + (long)blockIdx.x * SXc;
    const int tid = threadIdx.x;
    float v[4];
#pragma unroll
    for (int i = 0; i < 4; ++i) v[i] = sp[tid + 256 * i] * scale;
    float m = fmaxf(fmaxf(v[0], v[1]), fmaxf(v[2], v[3]));
    red[tid] = m; __syncthreads();
    for (int off = 128; off > 0; off >>= 1) {
        if (tid < off) red[tid] = fmaxf(red[tid], red[tid + off]);
        __syncthreads();
    }
    m = red[0]; __syncthreads();
    float e[4], sum = 0.f;
#pragma unroll
    for (int i = 0; i < 4; ++i) { e[i] = __expf(v[i] - m); sum += e[i]; }
    red[tid] = sum; __syncthreads();
    for (int off = 128; off > 0; off >>= 1) {
        if (tid < off) red[tid] += red[tid + off];
        __syncthreads();
    }
    const float inv = 1.0f / red[0];
#pragma unroll
    for (int i = 0; i < 4; ++i) {
        float a = e[i] * inv;
        sp[tid + 256 * i] = a;
        if (ab) ab[(long)blockIdx.x * SXc + tid + 256 * i] = __float2bfloat16(a);
    }
}

__global__ void relu_add_k(const bf16* __restrict__ h, const float* __restrict__ c,
                           bf16* __restrict__ y, float* __restrict__ out, long n)
{
    long i = (long)blockIdx.x * blockDim.x + threadIdx.x;
    if (i >= n) return;
    float v = __bfloat162float(h[i]) + c[i];
    v = v > 0.f ? v : 0.f;
    y[i] = __float2bfloat16(v);
    if (out) out[i] = v;
}

// all 3 int passthroughs in one launch
__global__ void pass_k(const int* __restrict__ tyb, const int* __restrict__ tei,
                       const int* __restrict__ tet, float* __restrict__ out)
{
    int i = blockIdx.x * blockDim.x + threadIdx.x;
    if (i < NYc) out[4194304 + i] = (float)tyb[i];
    else if (i < NYc + 2 * Ec) out[4210688 + (i - NYc)] = (float)tei[i - NYc];
    else if (i < NYc + 3 * Ec) out[4308992 + (i - NYc - 2 * Ec)] = (float)tet[i - NYc - 2 * Ec];
}

// per-node edge projection: ES[n][j]   = y3[n] . wg_top[:,j]   (j<5)
//                           ES[n][5+j] = y3[n] . wg_bot[:,j]
__global__ __launch_bounds__(256) void node_k(const bf16* __restrict__ y,
                                              const float* __restrict__ wg,
                                              float* __restrict__ ES)
{
    __shared__ float wgs[2560];
    for (int i = threadIdx.x; i < 2560; i += 256) wgs[i] = wg[i];
    __syncthreads();
    const int wid = threadIdx.x >> 6, l = threadIdx.x & 63;
    const int row = blockIdx.x * 4 + wid;
    const s4v yv = *(const s4v*)(y + (long)row * EMBdim + l * 4);
    float acc[10] = {0.f, 0.f, 0.f, 0.f, 0.f, 0.f, 0.f, 0.f, 0.f, 0.f};
#pragma unroll
    for (int c = 0; c < 4; ++c) {
        const float v = b2f(yv[c]);
        const float* wt = &wgs[(l * 4 + c) * 5];
        const float* wb = &wgs[(EMBdim + l * 4 + c) * 5];
#pragma unroll
        for (int j = 0; j < 5; ++j) {
            acc[j] = fmaf(v, wt[j], acc[j]);
            acc[5 + j] = fmaf(v, wb[j], acc[5 + j]);
        }
    }
#pragma unroll
    for (int j = 0; j < 10; ++j)
        for (int off = 32; off > 0; off >>= 1) acc[j] += __shfl_xor(acc[j], off);
    float* ep = ES + (long)row * 10;
#pragma unroll
    for (int j = 0; j < 10; ++j)
        if (l == j) ep[j] = acc[j];
}

// edge assembly: out[e][j] = ES[src][j] + ES[tgt][5+j] + bg[j]
__global__ void easm_k(const float* __restrict__ ES, const int* __restrict__ src,
                       const int* __restrict__ tgt, const float* __restrict__ bg,
                       float* __restrict__ out)
{
    int idx = blockIdx.x * blockDim.x + threadIdx.x;
    if (idx >= Ec * 5) return;
    int e = idx / 5, j = idx - e * 5;
    int s = src[e] & (NYc - 1), t = tgt[e] & (NYc - 1);
    out[idx] = ES[(long)s * 10 + j] + ES[(long)t * 10 + 5 + j] + bg[j];
}

// legacy edge (fallback path)
__global__ void edge_k(const bf16* __restrict__ y, const int* __restrict__ src,
                       const int* __restrict__ tgt, const float* __restrict__ wg,
                       const float* __restrict__ bg, float* __restrict__ out, int E)
{
    int idx = blockIdx.x * blockDim.x + threadIdx.x;
    if (idx >= E * 5) return;
    int e = idx / 5, j = idx - e * 5;
    int s = src[e] & (NYc - 1), t = tgt[e] & (NYc - 1);
    const bf16* ys = y + (long)s * EMBdim;
    const bf16* yt = y + (long)t * EMBdim;
    float acc = bg[j];
    for (int c = 0; c < EMBdim; ++c) acc = fmaf(__bfloat162float(ys[c]), wg[c * 5 + j], acc);
    for (int c = 0; c < EMBdim; ++c) acc = fmaf(__bfloat162float(yt[c]), wg[(EMBdim + c) * 5 + j], acc);
    out[idx] = acc;
}

// ================= fallback fp32 GEMM (known-good) =================
template <typename TA, typename TB, typename TC, bool TRANSB, bool ACC, bool BIAS>
__global__ __launch_bounds__(256) void gemm_k(
    const TA* __restrict__ A, const TB* __restrict__ B, TC* __restrict__ C,
    const float* __restrict__ bias, int M, int N, int K,
    long sA, long sB, long sC)
{
    A += (long)blockIdx.z * sA;
    B += (long)blockIdx.z * sB;
    C += (long)blockIdx.z * sC;
    __shared__ float As[8][128];
    __shared__ float Bs[8][132];
    const int tid = threadIdx.x;
    const int bm = blockIdx.y * 128;
    const int bn = blockIdx.x * 128;
    const int tx = tid & 15;
    const int ty = tid >> 4;
    float acc[8][8];
#pragma unroll
    for (int i = 0; i < 8; ++i)
#pragma unroll
        for (int j = 0; j < 8; ++j) acc[i][j] = 0.f;
    const int ar = tid >> 1;
    const int ac = (tid & 1) * 4;
    for (int k0 = 0; k0 < K; k0 += 8) {
        {
            const TA* ap = A + (long)(bm + ar) * K + (k0 + ac);
            float a0 = ldf(ap + 0), a1 = ldf(ap + 1), a2 = ldf(ap + 2), a3 = ldf(ap + 3);
            As[ac + 0][ar] = a0; As[ac + 1][ar] = a1;
            As[ac + 2][ar] = a2; As[ac + 3][ar] = a3;
        }
        if (!TRANSB) {
            const int bk = tid >> 5, bc = (tid & 31) * 4;
            const TB* bp = B + (long)(k0 + bk) * N + (bn + bc);
            Bs[bk][bc + 0] = ldf(bp + 0); Bs[bk][bc + 1] = ldf(bp + 1);
            Bs[bk][bc + 2] = ldf(bp + 2); Bs[bk][bc + 3] = ldf(bp + 3);
        } else {
            const int bn2 = tid >> 1, bc = (tid & 1) * 4;
            const TB* bp = B + (long)(bn + bn2) * K + (k0 + bc);
            Bs[bc + 0][bn2] = ldf(bp + 0); Bs[bc + 1][bn2] = ldf(bp + 1);
            Bs[bc + 2][bn2] = ldf(bp + 2); Bs[bc + 3][bn2] = ldf(bp + 3);
        }
        __syncthreads();
#pragma unroll
        for (int kk = 0; kk < 8; ++kk) {
            float a[8], b[8];
            *(f4v*)&a[0] = *(const f4v*)&As[kk][ty * 8];
            *(f4v*)&a[4] = *(const f4v*)&As[kk][ty * 8 + 4];
            *(f4v*)&b[0] = *(const f4v*)&Bs[kk][tx * 8];
            *(f4v*)&b[4] = *(const f4v*)&Bs[kk][tx * 8 + 4];
#pragma unroll
            for (int i = 0; i < 8; ++i)
#pragma unroll
                for (int j = 0; j < 8; ++j)
                    acc[i][j] = fmaf(a[i], b[j], acc[i][j]);
        }
        __syncthreads();
    }
#pragma unroll
    for (int i = 0; i < 8; ++i) {
        const int row = bm + ty * 8 + i;
#pragma unroll
        for (int j = 0; j < 8; ++j) {
            const int col = bn + tx * 8 + j;
            float v = acc[i][j];
            if (BIAS) v += bias[col];
            TC* cp = C + (long)row * N + col;
            if (ACC) v += ldf((const TC*)cp);
            stf(cp, v);
        }
    }
}

// ================= entry =================
#define T_W1S 0L
#define T_W1R 131072L
#define T_W1Q 655360L
#define T_W1K 917504L
#define T_W1V 1179648L
#define T_W2S 1441792L
#define T_W2R 1703936L
#define T_W2I 2752512L
#define T_W2Q 2883584L
#define T_W2K 3145728L
#define T_W2V 3407872L
#define T_W3S 3670016L
#define T_W3R 3801088L
#define T_W3I 4325376L
#define T_W3Q 4390912L
#define T_W3K 4456448L
#define T_W3V 4587520L
#define T_WZ  4718592L
#define WQWK_OFF 27541504L
#define XB_OFF   28311552L
#define Z5_OFF   36700160L
#define EMBF_OFF 57671680L
#define XT_OFF   57688064L
#define WCT_OFF  66076672L
#define ES_OFF   66404352L
#define WS_FAST_BYTES 301989888UL   // 288 MiB (evidence: ws poison fill ~870 MiB)

extern "C" void kernel_launch(void* const* d_in, const int* in_sizes, int n_in,
                              void* d_out, int out_size, void* d_ws, size_t ws_size,
                              hipStream_t stream)
{
    const float* x      = (const float*)d_in[0];
    const int*   tgt_y  = (const int*)d_in[2];
    const int*   tei    = (const int*)d_in[3];
    const int*   src    = tei;
    const int*   tgtI   = tei + Ec;
    const int*   tet    = (const int*)d_in[4];
    const int*   tyb    = (const int*)d_in[5];
    const float* embed  = (const float*)d_in[6];
    const float* w1_self = (const float*)d_in[7];
    const float* w1_rel  = (const float*)d_in[8];
    const float* w1_q    = (const float*)d_in[9];
    const float* w1_k    = (const float*)d_in[10];
    const float* w1_v    = (const float*)d_in[11];
    const float* w2_self = (const float*)d_in[12];
    const float* w2_rel  = (const float*)d_in[13];
    const float* w2_init = (const float*)d_in[14];
    const float* w2_q    = (const float*)d_in[15];
    const float* w2_k    = (const float*)d_in[16];
    const float* w2_v    = (const float*)d_in[17];
    const float* w3_self = (const float*)d_in[18];
    const float* w3_rel  = (const float*)d_in[19];
    const float* w3_init = (const float*)d_in[20];
    const float* w3_q    = (const float*)d_in[21];
    const float* w3_k    = (const float*)d_in[22];
    const float* w3_v    = (const float*)d_in[23];
    const float* wz      = (const float*)d_in[24];
    const float* bz      = (const float*)d_in[25];
    const float* wg      = (const float*)d_in[26];
    const float* bg      = (const float*)d_in[27];

    float* out = (float*)d_out;
    float* ws  = (float*)d_ws;

    float* o_y   = out;
    float* o_sc  = out + 4358144;
    float* o_ers = out + 6455296;
    float* o_a1  = out + 6701056;
    float* o_a2  = out + 23478272;
    float* o_a3  = out + 40255488;

    dim3 blk(256);

    if (ws_size >= WS_FAST_BYTES) {
        // ========= FAST PATH (MFMA, rank-128 y_init, x-factored attention) =======
        bf16* hbf   = (bf16*)ws;
        bf16* ibuf  = (bf16*)(ws + 4194304);
        bf16* abuf  = (bf16*)(ws + 8388608);   // ax (blocks 1/2); amir3 (block 3)
        bf16* ybuf  = (bf16*)(ws + 16777216);  // y; vT3 during attn3
        bf16* qbuf  = (bf16*)(ws + 20971520);  // y3buf upper 8MB
        bf16* y3buf = qbuf + 4194304;
        bf16* wbt   = (bf16*)(ws + 25165824);
        bf16* wq1n  = (bf16*)(ws + WQWK_OFF);              // non-transposed weights
        bf16* wk1n  = wq1n + 262144;
        bf16* wq2n  = wq1n + 524288;
        bf16* wk2n  = wq1n + 786432;
        bf16* wq3n  = wq1n + 1048576;                      // [256,256]
        bf16* wk3n  = wq1n + 1114112;                      // [512,256]
        bf16* xb    = (bf16*)(ws + XB_OFF);
        bf16* Z5    = (bf16*)(ws + Z5_OFF);
        bf16* scbf  = Z5;                                   // [NY,1024] bf16
        bf16* qkbuf = Z5 + 16777216;                        // [NY,512] bf16
        bf16* embf  = (bf16*)(ws + EMBF_OFF);
        bf16* xT    = (bf16*)(ws + XT_OFF);                 // per-batch [512][SXc]
        bf16* WcT1  = (bf16*)(ws + WCT_OFF);                // [512,512] x2
        bf16* WcT3  = WcT1 + 524288;                        // [512,256]
        float* ES   = ws + ES_OFF;                          // [NY,10] f32
        int* csr_ptr  = (int*)o_sc;
        int* csr_fill = csr_ptr + 16448;
        int* csr_cnt  = csr_ptr + 32832;
        int* csr_row  = csr_ptr + 49216;

        // ---- CSR build ----
        zeroi_k<<<(NYc + 255) / 256, blk, 0, stream>>>(csr_cnt, NYc);
        csr_cnt_k<<<(Ec + 255) / 256, blk, 0, stream>>>(tgtI, csr_cnt);
        csr_scan_k<<<1, blk, 0, stream>>>(csr_cnt, csr_ptr, csr_fill);
        csr_fill_k<<<(Ec + 255) / 256, blk, 0, stream>>>(src, tgtI, tet, csr_fill, csr_row);

        // ---- all weight transposes in ONE launch ----
        {
            WArg a;
            int i = 0;
            auto add = [&](const float* s, long d, int K, int N) {
                a.s[i] = s; a.d[i] = d; a.K[i] = K; a.N[i] = N; ++i;
            };
            add(w1_self, T_W1S, 256, 512);
            for (int z = 0; z < 4; ++z) add(w1_rel + (long)z * 131072, T_W1R + (long)z * 131072, 256, 512);
            add(w1_q, T_W1Q, 512, 512);
            add(w1_k, T_W1K, 512, 512);
            add(w1_v, T_W1V, 512, 512);
            add(w2_self, T_W2S, 512, 512);
            for (int z = 0; z < 4; ++z) add(w2_rel + (long)z * 262144, T_W2R + (long)z * 262144, 512, 512);
            add(w2_init, T_W2I, 256, 512);
            add(w2_q, T_W2Q, 512, 512);
            add(w2_k, T_W2K, 512, 512);
            add(w2_v, T_W2V, 512, 512);
            add(w3_self, T_W3S, 512, 256);
            for (int z = 0; z < 4; ++z) add(w3_rel + (long)z * 131072, T_W3R + (long)z * 131072, 512, 256);
            add(w3_init, T_W3I, 256, 256);
            add(w3_q, T_W3Q, 256, 256);
            add(w3_k, T_W3K, 512, 256);
            add(w3_v, T_W3V, 512, 256);
            add(wz, T_WZ, 256, 128);
            int tot = 0;
            for (int e = 0; e < NWENT; ++e) {
                a.t0[e] = tot;
                tot += (a.N[e] >> 5) * (a.K[e] >> 5);
            }
            a.t0[NWENT] = tot;
            wtrall_k<<<tot, blk, 0, stream>>>(a, wbt);
        }

        // ---- ALL f32->bf16 conversions in ONE launch ----
        {
            CvArg c;
            int i = 0;
            long tot = 0;
            auto add = [&](const float* s, bf16* d, long n8) {
                c.s[i] = s; c.d[i] = d; c.t0[i] = tot; tot += n8; ++i;
            };
            add(x, xb, (long)NXc * Fdim / 8);
            add(embed, embf, 4096);
            add(w1_q, wq1n, 32768);
            add(w1_k, wk1n, 32768);
            add(w2_q, wq2n, 32768);
            add(w2_k, wk2n, 32768);
            add(w3_q, wq3n, 8192);
            add(w3_k, wk3n, 16384);
            c.t0[NCENT] = tot;
            cvall_k<<<(int)((tot + 255) / 256), blk, 0, stream>>>(c);
        }

        // ---- WcT composites ----
        // WcT_b[f][i] = sum_o wk_b[f,o] wq_b[i,o]  (blocks 1/2, z-batched)
        mgemm_k<bf16, EP_BF16><<<dim3(4, 4, 2), blk, 0, stream>>>(
            wk1n, wq1n, nullptr, WcT1, nullptr, nullptr,
            512, 512, 512, 512, 512, 524288, 524288, 262144);
        // WcT3[f][i] = sum_o wk3[f,o] wq3[i,o]   [512,256]
        mgemm_k<bf16, EP_BF16><<<dim3(2, 4, 1), blk, 0, stream>>>(
            wk3n, wq3n, nullptr, WcT3, nullptr, nullptr,
            512, 256, 256, 256, 256, 0, 0, 0);

        // ---- xT (per-batch [512][SXc]) once ----
        vtr_k<<<dim3(NXc / 64, Fdim / 64, 1), blk, 0, stream>>>(xb, xT, Fdim, Fdim);

        // ---- x-factored attention for O=512 blocks ----
        auto attn12 = [&](const bf16* WcT, long twv, float* oa, bf16* amir) {
            mgemm_k<bf16, EP_BF16><<<dim3(4, 128, 1), blk, 0, stream>>>(
                hbf, WcT, nullptr, qkbuf, nullptr, nullptr,
                NYc, 512, 512, 512, 512, 0, 0, 0);
            mgemm_k<bf16, EP_BF16><<<dim3(8, 4, Bn), blk, 0, stream>>>(
                qkbuf, xb, nullptr, scbf, nullptr, nullptr,
                SYc, SXc, 512, 512, Fdim,
                (long)SYc * 512, (long)SXc * Fdim, (long)SYc * SXc);
            const float sc = 1.f / sqrtf(512.f);
            softmax3_k<<<NYc / 4, blk, 0, stream>>>(scbf, oa, amir, sc);
            mgemm_k<bf16, EP_BF16><<<dim3(4, 4, Bn), blk, 0, stream>>>(
                amir, xT, nullptr, abuf, nullptr, nullptr,
                SYc, Fdim, SXc, SXc, SXc,
                (long)SYc * SXc, 512L * SXc, (long)SYc * Fdim);
            mgemm_k<bf16, EP_RELUB><<<dim3(4, 128, 1), blk, 0, stream>>>(
                abuf, wbt + twv, nullptr, ybuf, (const float*)hbf, nullptr,
                NYc, 512, 512, 512, 512, 0, 0, 0);
        };

        // ---- block 1 ----
        mgemm_k<bf16, EP_BF16><<<dim3(20, 1, 1), blk, 0, stream>>>(
            embf, wbt + T_W1S, nullptr, Z5, nullptr, nullptr,
            128, 2560, INdim, INdim, INdim, 0, 0, 0);
        gather_k<<<(NYc << 6) / 256, blk, 0, stream>>>(
            Z5, csr_ptr, csr_row, nullptr, nullptr, tgt_y, hbf, 512, 6);
        attn12(WcT1, T_W1V, o_a1, (bf16*)o_a2);

        // ---- block 2 ----
        mgemm_k<bf16, EP_BF16><<<dim3(20, 128, 1), blk, 0, stream>>>(
            ybuf, wbt + T_W2S, nullptr, Z5, nullptr, nullptr,
            NYc, 2560, Hdim, Hdim, Hdim, 0, 0, 0);
        mgemm_k<bf16, EP_BF16><<<dim3(4, 1, 1), blk, 0, stream>>>(
            embf, wbt + T_W2I, nullptr, ibuf, nullptr, nullptr,
            128, 512, INdim, INdim, INdim, 0, 0, 0);
        gather_k<<<(NYc << 6) / 256, blk, 0, stream>>>(
            Z5, csr_ptr, csr_row, ibuf, tgt_y, nullptr, hbf, 512, 6);
        attn12(WcT1 + 262144, T_W2V, o_a2, (bf16*)o_a3);

        // ---- block 3 (Wc-factored scores, O=256) ----
        mgemm_k<bf16, EP_BF16><<<dim3(10, 128, 1), blk, 0, stream>>>(
            ybuf, wbt + T_W3S, nullptr, Z5, nullptr, nullptr,
            NYc, 1280, Hdim, Hdim, Hdim, 0, 0, 0);
        mgemm_k<bf16, EP_BF16><<<dim3(2, 1, 1), blk, 0, stream>>>(
            embf, wbt + T_W3I, nullptr, ibuf, nullptr, nullptr,
            128, 256, INdim, INdim, INdim, 0, 0, 0);
        gather_k<<<(NYc << 5) / 256, blk, 0, stream>>>(
            Z5, csr_ptr, csr_row, ibuf, tgt_y, nullptr, hbf, 256, 5);
        {
            const int O = 256;
            // qk3 = h3 @ Wc3  [NY,512]  (Z5 dead; qkbuf = Z5+32MB bytes, clear of scbf)
            mgemm_k<bf16, EP_BF16><<<dim3(4, 128, 1), blk, 0, stream>>>(
                hbf, WcT3, nullptr, qkbuf, nullptr, nullptr,
                NYc, 512, O, O, O, 0, 0, 0);
            // vT3 = wv3^T-GEMM: [O][NXc]  into ybuf (y2 dead after Z5-3 GEMM)
            mgemm_k<bf16, EP_BF16><<<dim3(256, O / 128, 1), blk, 0, stream>>>(
                wbt + T_W3V, xb, nullptr, ybuf, nullptr, nullptr,
                O, NXc, Fdim, Fdim, Fdim, 0, 0, 0);
            // scores3 = qk3 @ xb^T  (K=512)
            mgemm_k<bf16, EP_BF16><<<dim3(8, 4, Bn), blk, 0, stream>>>(
                qkbuf, xb, nullptr, scbf, nullptr, nullptr,
                SYc, SXc, 512, 512, Fdim,
                (long)SYc * 512, (long)SXc * Fdim, (long)SYc * SXc);
            const float sc = 1.f / sqrtf((float)O);
            softmax3_k<<<NYc / 4, blk, 0, stream>>>(scbf, o_a3, abuf, sc);
            // y3 = relu(h3 + alpha @ v3)   (B = vT3, ldB=NXc, per-batch col offset)
            mgemm_k<bf16, EP_RELUB><<<dim3(O / 128, 4, Bn), blk, 0, stream>>>(
                abuf, ybuf, o_y, y3buf, (const float*)hbf, nullptr,
                SYc, O, SXc, SXc, NXc,
                (long)SYc * SXc, (long)SXc, (long)SYc * O);
        }

        // ---- final scores (overwrites CSR scratch) + edge scores ----
        mgemm_k<bf16, EP_BIAS><<<dim3(1, 128, 1), blk, 0, stream>>>(
            y3buf, wbt + T_WZ, o_sc, nullptr, nullptr, bz,
            NYc, Vdim, EMBdim, EMBdim, EMBdim, 0, 0, 0);
        node_k<<<NYc / 4, blk, 0, stream>>>(y3buf, wg, ES);
        easm_k<<<(Ec * 5 + 255) / 256, blk, 0, stream>>>(ES, src, tgtI, bg, o_ers);
    } else {
        // ================= FALLBACK (fp32 FMA) =================
        bf16* y_init = (bf16*)o_y;
        embed_k<<<(NYc * 64 + 255) / 256, blk, 0, stream>>>(embed, tgt_y, y_init, NYc * 64);
        bf16* hbuf = (bf16*)ws;
        bf16* ybuf = (bf16*)(ws + 4194304);
        bf16* qc   = (bf16*)(ws + 8388608);
        bf16* kc   = (bf16*)(ws + 8912896);
        bf16* vc   = (bf16*)(ws + 9961472);
        float* ctxc = ws + 11010048;
        float* agg = o_a3;

        auto h_part = [&](const bf16* yin, int Din, const float* wself, const float* wrel,
                          const float* winit, int O) {
            gemm_k<bf16, float, bf16, false, false, false>
                <<<dim3(O / 128, 128, 1), blk, 0, stream>>>(yin, wself, hbuf, nullptr,
                                                            NYc, O, Din, 0, 0, 0);
            const int sh = (Din == 256) ? 6 : 7;
            for (int r = 0; r < 4; ++r) {
                zero_k<<<2048, blk, 0, stream>>>(agg, (long)NYc * Din / 4);
                scatter_k<<<((Ec << sh) + 255) / 256, blk, 0, stream>>>(yin, src, tgtI, tet,
                                                                        agg, Ec, sh, r);
                gemm_k<float, float, bf16, false, true, false>
                    <<<dim3(O / 128, 128, 1), blk, 0, stream>>>(agg, wrel + (long)r * Din * O,
                                                                hbuf, nullptr, NYc, O, Din, 0, 0, 0);
            }
            if (winit)
                gemm_k<bf16, float, bf16, false, true, false>
                    <<<dim3(O / 128, 128, 1), blk, 0, stream>>>(y_init, winit, hbuf, nullptr,
                                                                NYc, O, INdim, 0, 0, 0);
        };

        auto attn_relu = [&](const float* wq, const float* wk, const float* wv, int O,
                             float* aout, bf16* yb, float* oy) {
            const float sc = 1.f / sqrtf((float)O);
            for (int c = 0; c < NCHUNK; ++c) {
                const bf16* hc = hbuf + (long)c * YRc * O;
                const float* xc = x + (long)c * XRc * Fdim;
                float* ac = aout + (long)c * YRc * SXc;
                gemm_k<bf16, float, bf16, false, false, false>
                    <<<dim3(O / 128, YRc / 128, 1), blk, 0, stream>>>(hc, wq, qc, nullptr,
                                                                      YRc, O, O, 0, 0, 0);
                gemm_k<float, float, bf16, false, false, false>
                    <<<dim3(O / 128, XRc / 128, 1), blk, 0, stream>>>(xc, wk, kc, nullptr,
                                                                      XRc, O, Fdim, 0, 0, 0);
                gemm_k<float, float, bf16, false, false, false>
                    <<<dim3(O / 128, XRc / 128, 1), blk, 0, stream>>>(xc, wv, vc, nullptr,
                                                                      XRc, O, Fdim, 0, 0, 0);
                gemm_k<bf16, bf16, float, true, false, false>
                    <<<dim3(8, 4, CBc), blk, 0, stream>>>(qc, kc, ac, nullptr, SYc, SXc, O,
                                                          (long)SYc * O, (long)SXc * O,
                                                          (long)SYc * SXc);
                softmax2_k<<<YRc, blk, 0, stream>>>(ac, nullptr, sc);
                gemm_k<float, bf16, float, false, false, false>
                    <<<dim3(O / 128, 4, CBc), blk, 0, stream>>>(ac, vc, ctxc, nullptr, SYc, O,
                                                                SXc, (long)SYc * SXc,
                                                                (long)SXc * O, (long)SYc * O);
                long n = (long)YRc * O;
                relu_add_k<<<(int)((n + 255) / 256), blk, 0, stream>>>(
                    hc, ctxc, yb + (long)c * YRc * O, oy ? oy + (long)c * YRc * O : nullptr, n);
            }
        };

        h_part(y_init, 256, w1_self, w1_rel, nullptr, 512);
        attn_relu(w1_q, w1_k, w1_v, 512, o_a1, ybuf, nullptr);
        h_part(ybuf, 512, w2_self, w2_rel, w2_init, 512);
        attn_relu(w2_q, w2_k, w2_v, 512, o_a2, ybuf, nullptr);
        h_part(ybuf, 512, w3_self, w3_rel, w3_init, 256);
        attn_relu(w3_q, w3_k, w3_v, 256, o_a3, ybuf, o_y);

        gemm_k<bf16, float, float, false, false, true>
            <<<dim3(1, 128, 1), blk, 0, stream>>>(ybuf, wz, o_sc, bz, NYc, Vdim, EMBdim, 0, 0, 0);
        edge_k<<<(Ec * 5 + 255) / 256, blk, 0, stream>>>(ybuf, src, tgtI, wg, bg, o_ers, Ec);
    }

    // ---- int passthroughs (one launch) ----
    pass_k<<<(NYc + 3 * Ec + 255) / 256, blk, 0, stream>>>(tyb, tei, tet, out);
}

// Round 21
// 770.433 us; speedup vs baseline: 1.0058x; 1.0058x over previous
//
#include <hip/hip_runtime.h>
#include <hip/hip_bf16.h>
#include <cmath>

// ---------------- constants ----------------
#define Bn     32
#define SYc    512
#define SXc    1024
#define Fdim   512
#define INdim  256
#define Hdim   512
#define EMBdim 256
#define Vdim   128
#define NYc    16384
#define NXc    32768
#define Ec     49152
#define CBc    4
#define NCHUNK (Bn / CBc)
#define YRc    (CBc * SYc)
#define XRc    (CBc * SXc)

typedef float f4v __attribute__((ext_vector_type(4)));
typedef short s8v __attribute__((ext_vector_type(8)));
typedef short s4v __attribute__((ext_vector_type(4)));
typedef __hip_bfloat16 bf16;

__device__ __forceinline__ float ldf(const float* p) { return *p; }
__device__ __forceinline__ float ldf(const bf16* p) { return __bfloat162float(*p); }
__device__ __forceinline__ void stf(float* p, float v) { *p = v; }
__device__ __forceinline__ void stf(bf16* p, float v) { *p = __float2bfloat16(v); }
__device__ __forceinline__ short f2b(float x) {
    bf16 h = __float2bfloat16(x);
    return *reinterpret_cast<const short*>(&h);
}
__device__ __forceinline__ float b2f(short s) {
    bf16 h = *reinterpret_cast<const bf16*>(&s);
    return __bfloat162float(h);
}

// async global->LDS, 16B per lane; dst = base + lane*16 (wave-uniform base)
__device__ __forceinline__ void gload16(const void* g, void* l) {
    __builtin_amdgcn_global_load_lds((const __attribute__((address_space(1))) void*)g,
                                     (__attribute__((address_space(3))) void*)l, 16, 0, 0);
}

// ================= MFMA bf16 GEMM =================
enum { EP_F32 = 0, EP_F32ACC, EP_BF16, EP_RELUB, EP_BIAS };

template <typename TA, int EP>
__global__ __launch_bounds__(256) void mgemm_k(
    const TA* __restrict__ A, const bf16* __restrict__ BT,
    float* __restrict__ Cf, bf16* __restrict__ Cb,
    const float* __restrict__ H, const float* __restrict__ bias,
    int M, int N, int K, int ldA, int ldB,
    long sA, long sB, long sC)
{
    __shared__ s8v As[512];   // unit u = row*4 + slot; slot = (kp + (row>>1))&3
    __shared__ s8v Bs[512];
    // XCD-aware bijective swizzle (m204)
    const int nwg = gridDim.x * gridDim.y;
    const int flat = blockIdx.y * gridDim.x + blockIdx.x;
    const int qd = nwg >> 3, rm = nwg & 7;
    const int xcd = flat & 7, base = flat >> 3;
    const int wgid = (xcd < rm ? xcd * (qd + 1) : rm * (qd + 1) + (xcd - rm) * qd) + base;
    const int bx = wgid % gridDim.x, by = wgid / gridDim.x;

    const int tid = threadIdx.x;
    const int l = tid & 63, w = tid >> 6;
    const int wr = w >> 1, wc = w & 1;
    const long bm = (long)by * 128, bn = (long)bx * 128;
    const int z = blockIdx.z;
    const TA* Ab = A + (long)z * sA;
    const bf16* Bb = BT + (long)z * sB;
    const int l15 = l & 15, kq = l >> 4;

    f4v acc[4][4];
#pragma unroll
    for (int i = 0; i < 4; ++i)
#pragma unroll
        for (int j = 0; j < 4; ++j) acc[i][j] = f4v{0.f, 0.f, 0.f, 0.f};

    for (int k0 = 0; k0 < K; k0 += 32) {
        if constexpr (sizeof(TA) == 2) {
#pragma unroll
            for (int i = 0; i < 2; ++i) {
                const int u = w * 128 + i * 64 + l;
                const int row = u >> 2, slot = u & 3;
                const int kp = (slot - (row >> 1)) & 3;
                gload16((const bf16*)Ab + (bm + row) * (long)ldA + k0 + kp * 8,
                        &As[w * 128 + i * 64]);
                gload16(Bb + (bn + row) * (long)ldB + k0 + kp * 8,
                        &Bs[w * 128 + i * 64]);
            }
        } else {
#pragma unroll
            for (int j = 0; j < 2; ++j) {
                const int id = tid * 2 + j;
                const int row = id >> 2, kp = id & 3;
                const int slot = (kp + (row >> 1)) & 3;
                const float* ap = (const float*)Ab + (bm + row) * (long)ldA + k0 + kp * 8;
                f4v v0 = *(const f4v*)ap, v1 = *(const f4v*)(ap + 4);
                s8v t;
                t[0] = f2b(v0.x); t[1] = f2b(v0.y); t[2] = f2b(v0.z); t[3] = f2b(v0.w);
                t[4] = f2b(v1.x); t[5] = f2b(v1.y); t[6] = f2b(v1.z); t[7] = f2b(v1.w);
                As[row * 4 + slot] = t;
            }
#pragma unroll
            for (int i = 0; i < 2; ++i) {
                const int u = w * 128 + i * 64 + l;
                const int row = u >> 2, slot = u & 3;
                const int kp = (slot - (row >> 1)) & 3;
                gload16(Bb + (bn + row) * (long)ldB + k0 + kp * 8,
                        &Bs[w * 128 + i * 64]);
            }
        }
        __syncthreads();
        s8v af[4], bfr[4];
#pragma unroll
        for (int f = 0; f < 4; ++f) {
            const int ar = wr * 64 + f * 16 + l15;
            af[f] = As[ar * 4 + ((kq + (ar >> 1)) & 3)];
            const int br = wc * 64 + f * 16 + l15;
            bfr[f] = Bs[br * 4 + ((kq + (br >> 1)) & 3)];
        }
#pragma unroll
        for (int i = 0; i < 4; ++i)
#pragma unroll
            for (int j = 0; j < 4; ++j)
                acc[i][j] = __builtin_amdgcn_mfma_f32_16x16x32_bf16(af[i], bfr[j], acc[i][j], 0, 0, 0);
        __syncthreads();
    }

#pragma unroll
    for (int i = 0; i < 4; ++i)
#pragma unroll
        for (int j = 0; j < 4; ++j)
#pragma unroll
            for (int r = 0; r < 4; ++r) {
                const long row = bm + wr * 64 + i * 16 + kq * 4 + r;
                const long col = bn + wc * 64 + j * 16 + l15;
                const long idx = (long)z * sC + row * N + col;
                float v = acc[i][j][r];
                if constexpr (EP == EP_F32) Cf[idx] = v;
                else if constexpr (EP == EP_F32ACC) Cf[idx] += v;
                else if constexpr (EP == EP_BF16) Cb[idx] = __float2bfloat16(v);
                else if constexpr (EP == EP_BIAS) Cf[idx] = v + bias[col];
                else {  // EP_RELUB
                    v += __bfloat162float(((const bf16*)H)[idx]);
                    v = fmaxf(v, 0.f);
                    Cb[idx] = __float2bfloat16(v);
                    if (Cf) Cf[idx] = v;
                }
            }
}

// ================= batched weight transpose (ALL weights, one launch) ==========
#define NWENT 27
struct WArg {
    const float* s[NWENT];
    long d[NWENT];
    int K[NWENT], N[NWENT];
    int t0[NWENT + 1];
};

__global__ __launch_bounds__(256) void wtrall_k(WArg a, bf16* __restrict__ wbt)
{
    __shared__ float T[32][33];
    int b = blockIdx.x;
    int e = 0;
    while (b >= a.t0[e + 1]) ++e;
    const int lt = b - a.t0[e];
    const int K = a.K[e], N = a.N[e];
    const int tx = N >> 5;
    const int n0 = (lt % tx) * 32, k0 = (lt / tx) * 32;
    const float* src = a.s[e];
    bf16* dst = wbt + a.d[e];
    const int t = threadIdx.x;
    const int kr = t >> 3, nc = (t & 7) * 4;
    f4v v = *(const f4v*)(src + (long)(k0 + kr) * N + n0 + nc);
    T[kr][nc] = v.x; T[kr][nc + 1] = v.y; T[kr][nc + 2] = v.z; T[kr][nc + 3] = v.w;
    __syncthreads();
    const int nr = t >> 3, kc = (t & 7) * 4;
    bf16* dp = dst + (long)(n0 + nr) * K + k0 + kc;
    dp[0] = __float2bfloat16(T[kc][nr]);
    dp[1] = __float2bfloat16(T[kc + 1][nr]);
    dp[2] = __float2bfloat16(T[kc + 2][nr]);
    dp[3] = __float2bfloat16(T[kc + 3][nr]);
}

// ================= batched f32->bf16 convert (6 tensors, one launch) ==========
#define NCENT 6
struct CvArg {
    const float* s[NCENT];
    bf16* d[NCENT];
    long t0[NCENT + 1];   // prefix in 8-elem groups
};

__global__ void cvall_k(CvArg a)
{
    long idx = (long)blockIdx.x * blockDim.x + threadIdx.x;
    if (idx >= a.t0[NCENT]) return;
    int e = 0;
    while (idx >= a.t0[e + 1]) ++e;
    const long g = idx - a.t0[e];
    const f4v v0 = ((const f4v*)a.s[e])[g * 2], v1 = ((const f4v*)a.s[e])[g * 2 + 1];
    s8v t;
    t[0] = f2b(v0.x); t[1] = f2b(v0.y); t[2] = f2b(v0.z); t[3] = f2b(v0.w);
    t[4] = f2b(v1.x); t[5] = f2b(v1.y); t[6] = f2b(v1.z); t[7] = f2b(v1.w);
    ((s8v*)a.d[e])[g] = t;
}

// v transpose: bf16 [NXc][ldIn] (cols [0,C)) -> per-batch [C][SXc]
__global__ __launch_bounds__(256) void vtr_k(const bf16* __restrict__ in,
                                             bf16* __restrict__ outp, int C, int ldIn)
{
    __shared__ short T[64][72];
    const int r0 = blockIdx.x * 64, c0 = blockIdx.y * 64;
    const int t = threadIdx.x;
    const int rr = t >> 2, cc = (t & 3) * 16;
    const bf16* ip = in + (long)(r0 + rr) * ldIn + c0 + cc;
    *(s8v*)&T[rr][cc] = *(const s8v*)ip;
    *(s8v*)&T[rr][cc + 8] = *(const s8v*)(ip + 8);
    __syncthreads();
    const int cr = t >> 2, rs = (t & 3) * 16;
    const int b = r0 >> 10, s0 = r0 & 1023;
    bf16* dp = outp + ((long)b * C + (c0 + cr)) * SXc + s0 + rs;
    s8v o0, o1;
#pragma unroll
    for (int i = 0; i < 8; ++i) { o0[i] = T[rs + i][cr]; o1[i] = T[rs + 8 + i][cr]; }
    *(s8v*)dp = o0;
    *(s8v*)(dp + 8) = o1;
}

// ================= CSR build =================
__global__ void zeroi_k(int* __restrict__ p, int n)
{
    int i = blockIdx.x * blockDim.x + threadIdx.x;
    if (i < n) p[i] = 0;
}

__global__ void csr_cnt_k(const int* __restrict__ tgt, int* __restrict__ cnt)
{
    int e = blockIdx.x * blockDim.x + threadIdx.x;
    if (e < Ec) atomicAdd(&cnt[tgt[e] & (NYc - 1)], 1);
}

__global__ __launch_bounds__(256) void csr_scan_k(const int* __restrict__ cnt,
                                                  int* __restrict__ ptr,
                                                  int* __restrict__ pfill)
{
    __shared__ int ps[256];
    const int t = threadIdx.x;
    const int base = t * 64;
    int sum = 0;
    for (int i = 0; i < 64; ++i) sum += cnt[base + i];
    ps[t] = sum;
    __syncthreads();
    for (int off = 1; off < 256; off <<= 1) {
        int v = (t >= off) ? ps[t - off] : 0;
        __syncthreads();
        ps[t] += v;
        __syncthreads();
    }
    int run = (t == 0) ? 0 : ps[t - 1];
    for (int i = 0; i < 64; ++i) {
        ptr[base + i] = run;
        pfill[base + i] = run;
        run += cnt[base + i];
    }
    if (t == 255) ptr[NYc] = run;
}

__global__ void csr_fill_k(const int* __restrict__ src, const int* __restrict__ tgt,
                           const int* __restrict__ et, int* __restrict__ pfill,
                           int* __restrict__ srcrow)
{
    int e = blockIdx.x * blockDim.x + threadIdx.x;
    if (e >= Ec) return;
    int t = tgt[e] & (NYc - 1);
    int pos = atomicAdd(&pfill[t], 1);
    srcrow[pos] = ((src[e] & (NYc - 1)) << 2) | (et[e] & 3);
}

// h(bf16) = Z5.self[zrow(t)] + sum_{edges->t} Z5.rel[et][zrow(src)] (+ ib[irow(t)]).
__global__ __launch_bounds__(256) void gather_k(const bf16* __restrict__ Z5,
                                                const int* __restrict__ ptr,
                                                const int* __restrict__ srcrow,
                                                const bf16* __restrict__ ib,
                                                const int* __restrict__ imap,
                                                const int* __restrict__ zmap,
                                                bf16* __restrict__ hbf,
                                                int O, int sh3 /*log2(O/8)*/)
{
    int idx = blockIdx.x * blockDim.x + threadIdx.x;
    int t = idx >> sh3;
    int c8 = (idx & ((1 << sh3) - 1)) * 8;
    const long fiveO = 5L * O;
    float s[8];
    {
        const int zt = zmap ? (zmap[t] & (Vdim - 1)) : t;
        const s8v v = *(const s8v*)(Z5 + (long)zt * fiveO + c8);
#pragma unroll
        for (int j = 0; j < 8; ++j) s[j] = b2f(v[j]);
    }
    if (ib) {
        const int it = imap ? (imap[t] & (Vdim - 1)) : t;
        const s8v v = *(const s8v*)(ib + (long)it * O + c8);
#pragma unroll
        for (int j = 0; j < 8; ++j) s[j] += b2f(v[j]);
    }
    const int beg = ptr[t], end = ptr[t + 1];
    for (int i = beg; i < end; ++i) {
        const int sr = srcrow[i];
        int srow = sr >> 2;
        const int et = sr & 3;
        if (zmap) srow = zmap[srow] & (Vdim - 1);
        const s8v v = *(const s8v*)(Z5 + (long)srow * fiveO + (long)(1 + et) * O + c8);
#pragma unroll
        for (int j = 0; j < 8; ++j) s[j] += b2f(v[j]);
    }
    s8v hv;
#pragma unroll
    for (int j = 0; j < 8; ++j) hv[j] = f2b(s[j]);
    *(s8v*)(hbf + (long)t * O + c8) = hv;
}

// ================= shared small kernels =================
__global__ void embed_k(const float* __restrict__ embed, const int* __restrict__ ids,
                        bf16* __restrict__ y, int n)
{
    int idx = blockIdx.x * blockDim.x + threadIdx.x;
    if (idx >= n) return;
    int row = idx >> 6, q = idx & 63;
    int id = ids[row] & (Vdim - 1);
    f4v v = ((const f4v*)embed)[(long)id * 64 + q];
    bf16* yp = y + (long)row * 256 + q * 4;
    yp[0] = __float2bfloat16(v.x); yp[1] = __float2bfloat16(v.y);
    yp[2] = __float2bfloat16(v.z); yp[3] = __float2bfloat16(v.w);
}

// legacy scatter (fallback path)
__global__ void scatter_k(const bf16* __restrict__ y, const int* __restrict__ src,
                          const int* __restrict__ tgt, const int* __restrict__ et,
                          float* __restrict__ agg, int E, int sh, int r)
{
    int idx = blockIdx.x * blockDim.x + threadIdx.x;
    if (idx >= (E << sh)) return;
    int e = idx >> sh;
    if ((et[e] & 3) != r) return;
    int c = (idx & ((1 << sh) - 1)) * 4;
    int D = 4 << sh;
    int s = src[e] & (NYc - 1);
    int t = tgt[e] & (NYc - 1);
    const bf16* yp = y + (long)s * D + c;
    float* ap = agg + (long)t * D + c;
    atomicAdd(ap + 0, __bfloat162float(yp[0]));
    atomicAdd(ap + 1, __bfloat162float(yp[1]));
    atomicAdd(ap + 2, __bfloat162float(yp[2]));
    atomicAdd(ap + 3, __bfloat162float(yp[3]));
}

__global__ void zero_k(float* __restrict__ p, long n4)
{
    long i = (long)blockIdx.x * blockDim.x + threadIdx.x;
    const long stride = (long)gridDim.x * blockDim.x;
    for (; i < n4; i += stride) ((f4v*)p)[i] = f4v{0.f, 0.f, 0.f, 0.f};
}

// softmax: wave-per-row; bf16 scores -> f32 alpha + bf16 mirror
__global__ __launch_bounds__(256) void softmax3_k(const bf16* __restrict__ sin,
                                                  float* __restrict__ aout,
                                                  bf16* __restrict__ amir, float scale)
{
    const int wid = threadIdx.x >> 6;
    const int l = threadIdx.x & 63;
    const long row = (long)blockIdx.x * 4 + wid;
    const bf16* sp = sin + row * SXc + l * 16;
    float v[16];
    {
        const s8v a0 = *(const s8v*)sp;
        const s8v a1 = *(const s8v*)(sp + 8);
#pragma unroll
        for (int i = 0; i < 8; ++i) { v[i] = b2f(a0[i]) * scale; v[8 + i] = b2f(a1[i]) * scale; }
    }
    float m = v[0];
#pragma unroll
    for (int i = 1; i < 16; ++i) m = fmaxf(m, v[i]);
    for (int off = 32; off > 0; off >>= 1) m = fmaxf(m, __shfl_xor(m, off));
    float sum = 0.f;
#pragma unroll
    for (int i = 0; i < 16; ++i) { v[i] = __expf(v[i] - m); sum += v[i]; }
    for (int off = 32; off > 0; off >>= 1) sum += __shfl_xor(sum, off);
    const float inv = 1.0f / sum;
    float* ap = aout + row * SXc + l * 16;
    bf16* mp = amir + row * SXc + l * 16;
    f4v o0, o1, o2, o3;
    s8v m0, m1;
#pragma unroll
    for (int i = 0; i < 4; ++i) {
        o0[i] = v[i] * inv; o1[i] = v[4 + i] * inv;
        o2[i] = v[8 + i] * inv; o3[i] = v[12 + i] * inv;
    }
#pragma unroll
    for (int i = 0; i < 8; ++i) { m0[i] = f2b(v[i] * inv); m1[i] = f2b(v[8 + i] * inv); }
    ((f4v*)ap)[0] = o0; ((f4v*)ap)[1] = o1; ((f4v*)ap)[2] = o2; ((f4v*)ap)[3] = o3;
    *(s8v*)mp = m0; *(s8v*)(mp + 8) = m1;
}

// softmax in-place f32 (fallback path)
__global__ __launch_bounds__(256) void softmax2_k(float* __restrict__ s,
                                                  bf16* __restrict__ ab, float scale)
{
    __shared__ float red[256];
    float* sp = s + (long)blockIdx.x * SXc;
    const int tid = threadIdx.x;
    float v[4];
#pragma unroll
    for (int i = 0; i < 4; ++i) v[i] = sp[tid + 256 * i] * scale;
    float m = fmaxf(fmaxf(v[0], v[1]), fmaxf(v[2], v[3]));
    red[tid] = m; __syncthreads();
    for (int off = 128; off > 0; off >>= 1) {
        if (tid < off) red[tid] = fmaxf(red[tid], red[tid + off]);
        __syncthreads();
    }
    m = red[0]; __syncthreads();
    float e[4], sum = 0.f;
#pragma unroll
    for (int i = 0; i < 4; ++i) { e[i] = __expf(v[i] - m); sum += e[i]; }
    red[tid] = sum; __syncthreads();
    for (int off = 128; off > 0; off >>= 1) {
        if (tid < off) red[tid] += red[tid + off];
        __syncthreads();
    }
    const float inv = 1.0f / red[0];
#pragma unroll
    for (int i = 0; i < 4; ++i) {
        float a = e[i] * inv;
        sp[tid + 256 * i] = a;
        if (ab) ab[(long)blockIdx.x * SXc + tid + 256 * i] = __float2bfloat16(a);
    }
}

__global__ void relu_add_k(const bf16* __restrict__ h, const float* __restrict__ c,
                           bf16* __restrict__ y, float* __restrict__ out, long n)
{
    long i = (long)blockIdx.x * blockDim.x + threadIdx.x;
    if (i >= n) return;
    float v = __bfloat162float(h[i]) + c[i];
    v = v > 0.f ? v : 0.f;
    y[i] = __float2bfloat16(v);
    if (out) out[i] = v;
}

// all 3 int passthroughs in one launch
__global__ void pass_k(const int* __restrict__ tyb, const int* __restrict__ tei,
                       const int* __restrict__ tet, float* __restrict__ out)
{
    int i = blockIdx.x * blockDim.x + threadIdx.x;
    if (i < NYc) out[4194304 + i] = (float)tyb[i];
    else if (i < NYc + 2 * Ec) out[4210688 + (i - NYc)] = (float)tei[i - NYc];
    else if (i < NYc + 3 * Ec) out[4308992 + (i - NYc - 2 * Ec)] = (float)tet[i - NYc - 2 * Ec];
}

// per-node edge projection: ES[n][j]   = y3[n] . wg_top[:,j]   (j<5)
//                           ES[n][5+j] = y3[n] . wg_bot[:,j]
__global__ __launch_bounds__(256) void node_k(const bf16* __restrict__ y,
                                              const float* __restrict__ wg,
                                              float* __restrict__ ES)
{
    __shared__ float wgs[2560];
    for (int i = threadIdx.x; i < 2560; i += 256) wgs[i] = wg[i];
    __syncthreads();
    const int wid = threadIdx.x >> 6, l = threadIdx.x & 63;
    const int row = blockIdx.x * 4 + wid;
    const s4v yv = *(const s4v*)(y + (long)row * EMBdim + l * 4);
    float acc[10] = {0.f, 0.f, 0.f, 0.f, 0.f, 0.f, 0.f, 0.f, 0.f, 0.f};
#pragma unroll
    for (int c = 0; c < 4; ++c) {
        const float v = b2f(yv[c]);
        const float* wt = &wgs[(l * 4 + c) * 5];
        const float* wb = &wgs[(EMBdim + l * 4 + c) * 5];
#pragma unroll
        for (int j = 0; j < 5; ++j) {
            acc[j] = fmaf(v, wt[j], acc[j]);
            acc[5 + j] = fmaf(v, wb[j], acc[5 + j]);
        }
    }
#pragma unroll
    for (int j = 0; j < 10; ++j)
        for (int off = 32; off > 0; off >>= 1) acc[j] += __shfl_xor(acc[j], off);
    float* ep = ES + (long)row * 10;
#pragma unroll
    for (int j = 0; j < 10; ++j)
        if (l == j) ep[j] = acc[j];
}

// edge assembly: out[e][j] = ES[src][j] + ES[tgt][5+j] + bg[j]
__global__ void easm_k(const float* __restrict__ ES, const int* __restrict__ src,
                       const int* __restrict__ tgt, const float* __restrict__ bg,
                       float* __restrict__ out)
{
    int idx = blockIdx.x * blockDim.x + threadIdx.x;
    if (idx >= Ec * 5) return;
    int e = idx / 5, j = idx - e * 5;
    int s = src[e] & (NYc - 1), t = tgt[e] & (NYc - 1);
    out[idx] = ES[(long)s * 10 + j] + ES[(long)t * 10 + 5 + j] + bg[j];
}

// legacy edge (fallback path)
__global__ void edge_k(const bf16* __restrict__ y, const int* __restrict__ src,
                       const int* __restrict__ tgt, const float* __restrict__ wg,
                       const float* __restrict__ bg, float* __restrict__ out, int E)
{
    int idx = blockIdx.x * blockDim.x + threadIdx.x;
    if (idx >= E * 5) return;
    int e = idx / 5, j = idx - e * 5;
    int s = src[e] & (NYc - 1), t = tgt[e] & (NYc - 1);
    const bf16* ys = y + (long)s * EMBdim;
    const bf16* yt = y + (long)t * EMBdim;
    float acc = bg[j];
    for (int c = 0; c < EMBdim; ++c) acc = fmaf(__bfloat162float(ys[c]), wg[c * 5 + j], acc);
    for (int c = 0; c < EMBdim; ++c) acc = fmaf(__bfloat162float(yt[c]), wg[(EMBdim + c) * 5 + j], acc);
    out[idx] = acc;
}

// ================= fallback fp32 GEMM (known-good) =================
template <typename TA, typename TB, typename TC, bool TRANSB, bool ACC, bool BIAS>
__global__ __launch_bounds__(256) void gemm_k(
    const TA* __restrict__ A, const TB* __restrict__ B, TC* __restrict__ C,
    const float* __restrict__ bias, int M, int N, int K,
    long sA, long sB, long sC)
{
    A += (long)blockIdx.z * sA;
    B += (long)blockIdx.z * sB;
    C += (long)blockIdx.z * sC;
    __shared__ float As[8][128];
    __shared__ float Bs[8][132];
    const int tid = threadIdx.x;
    const int bm = blockIdx.y * 128;
    const int bn = blockIdx.x * 128;
    const int tx = tid & 15;
    const int ty = tid >> 4;
    float acc[8][8];
#pragma unroll
    for (int i = 0; i < 8; ++i)
#pragma unroll
        for (int j = 0; j < 8; ++j) acc[i][j] = 0.f;
    const int ar = tid >> 1;
    const int ac = (tid & 1) * 4;
    for (int k0 = 0; k0 < K; k0 += 8) {
        {
            const TA* ap = A + (long)(bm + ar) * K + (k0 + ac);
            float a0 = ldf(ap + 0), a1 = ldf(ap + 1), a2 = ldf(ap + 2), a3 = ldf(ap + 3);
            As[ac + 0][ar] = a0; As[ac + 1][ar] = a1;
            As[ac + 2][ar] = a2; As[ac + 3][ar] = a3;
        }
        if (!TRANSB) {
            const int bk = tid >> 5, bc = (tid & 31) * 4;
            const TB* bp = B + (long)(k0 + bk) * N + (bn + bc);
            Bs[bk][bc + 0] = ldf(bp + 0); Bs[bk][bc + 1] = ldf(bp + 1);
            Bs[bk][bc + 2] = ldf(bp + 2); Bs[bk][bc + 3] = ldf(bp + 3);
        } else {
            const int bn2 = tid >> 1, bc = (tid & 1) * 4;
            const TB* bp = B + (long)(bn + bn2) * K + (k0 + bc);
            Bs[bc + 0][bn2] = ldf(bp + 0); Bs[bc + 1][bn2] = ldf(bp + 1);
            Bs[bc + 2][bn2] = ldf(bp + 2); Bs[bc + 3][bn2] = ldf(bp + 3);
        }
        __syncthreads();
#pragma unroll
        for (int kk = 0; kk < 8; ++kk) {
            float a[8], b[8];
            *(f4v*)&a[0] = *(const f4v*)&As[kk][ty * 8];
            *(f4v*)&a[4] = *(const f4v*)&As[kk][ty * 8 + 4];
            *(f4v*)&b[0] = *(const f4v*)&Bs[kk][tx * 8];
            *(f4v*)&b[4] = *(const f4v*)&Bs[kk][tx * 8 + 4];
#pragma unroll
            for (int i = 0; i < 8; ++i)
#pragma unroll
                for (int j = 0; j < 8; ++j)
                    acc[i][j] = fmaf(a[i], b[j], acc[i][j]);
        }
        __syncthreads();
    }
#pragma unroll
    for (int i = 0; i < 8; ++i) {
        const int row = bm + ty * 8 + i;
#pragma unroll
        for (int j = 0; j < 8; ++j) {
            const int col = bn + tx * 8 + j;
            float v = acc[i][j];
            if (BIAS) v += bias[col];
            TC* cp = C + (long)row * N + col;
            if (ACC) v += ldf((const TC*)cp);
            stf(cp, v);
        }
    }
}

// ================= entry =================
#define T_W1S 0L
#define T_W1R 131072L
#define T_W1Q 655360L
#define T_W1K 917504L
#define T_W1V 1179648L
#define T_W2S 1441792L
#define T_W2R 1703936L
#define T_W2I 2752512L
#define T_W2Q 2883584L
#define T_W2K 3145728L
#define T_W2V 3407872L
#define T_W3S 3670016L
#define T_W3R 3801088L
#define T_W3I 4325376L
#define T_W3Q 4390912L
#define T_W3K 4456448L
#define T_W3V 4587520L
#define T_WZ  4718592L
#define WQWK_OFF 27541504L
#define XB_OFF   28311552L
#define Z5_OFF   36700160L
#define EMBF_OFF 57671680L
#define XT_OFF   57688064L
#define WCT_OFF  66076672L
#define ES_OFF   66338816L
#define WS_FAST_BYTES 301989888UL   // 288 MiB (evidence: ws poison fill ~870 MiB)

extern "C" void kernel_launch(void* const* d_in, const int* in_sizes, int n_in,
                              void* d_out, int out_size, void* d_ws, size_t ws_size,
                              hipStream_t stream)
{
    const float* x      = (const float*)d_in[0];
    const int*   tgt_y  = (const int*)d_in[2];
    const int*   tei    = (const int*)d_in[3];
    const int*   src    = tei;
    const int*   tgtI   = tei + Ec;
    const int*   tet    = (const int*)d_in[4];
    const int*   tyb    = (const int*)d_in[5];
    const float* embed  = (const float*)d_in[6];
    const float* w1_self = (const float*)d_in[7];
    const float* w1_rel  = (const float*)d_in[8];
    const float* w1_q    = (const float*)d_in[9];
    const float* w1_k    = (const float*)d_in[10];
    const float* w1_v    = (const float*)d_in[11];
    const float* w2_self = (const float*)d_in[12];
    const float* w2_rel  = (const float*)d_in[13];
    const float* w2_init = (const float*)d_in[14];
    const float* w2_q    = (const float*)d_in[15];
    const float* w2_k    = (const float*)d_in[16];
    const float* w2_v    = (const float*)d_in[17];
    const float* w3_self = (const float*)d_in[18];
    const float* w3_rel  = (const float*)d_in[19];
    const float* w3_init = (const float*)d_in[20];
    const float* w3_q    = (const float*)d_in[21];
    const float* w3_k    = (const float*)d_in[22];
    const float* w3_v    = (const float*)d_in[23];
    const float* wz      = (const float*)d_in[24];
    const float* bz      = (const float*)d_in[25];
    const float* wg      = (const float*)d_in[26];
    const float* bg      = (const float*)d_in[27];

    float* out = (float*)d_out;
    float* ws  = (float*)d_ws;

    float* o_y   = out;
    float* o_sc  = out + 4358144;
    float* o_ers = out + 6455296;
    float* o_a1  = out + 6701056;
    float* o_a2  = out + 23478272;
    float* o_a3  = out + 40255488;

    dim3 blk(256);

    if (ws_size >= WS_FAST_BYTES) {
        // ========= FAST PATH (MFMA, rank-128 y_init, x-factored attention) =======
        bf16* hbf   = (bf16*)ws;
        bf16* ibuf  = (bf16*)(ws + 4194304);
        bf16* abuf  = (bf16*)(ws + 8388608);   // ax (blocks 1/2); k3+amir3 (block 3)
        bf16* ybuf  = (bf16*)(ws + 16777216);  // y; vT3 during attn3
        bf16* qbuf  = (bf16*)(ws + 20971520);  // q3; y3buf upper 8MB
        bf16* y3buf = qbuf + 4194304;
        bf16* wbt   = (bf16*)(ws + 25165824);
        bf16* wq1n  = (bf16*)(ws + WQWK_OFF);              // [512,512] non-transposed
        bf16* wk1n  = wq1n + 262144;
        bf16* wq2n  = wq1n + 524288;
        bf16* wk2n  = wq1n + 786432;
        bf16* xb    = (bf16*)(ws + XB_OFF);
        bf16* Z5    = (bf16*)(ws + Z5_OFF);
        bf16* scbf  = Z5;                                   // [NY,1024] bf16
        bf16* qkbuf = Z5 + 16777216;                        // [NY,512] bf16
        bf16* embf  = (bf16*)(ws + EMBF_OFF);
        bf16* xT    = (bf16*)(ws + XT_OFF);                 // per-batch [512][SXc]
        bf16* WcT1  = (bf16*)(ws + WCT_OFF);                // [512,512]
        float* ES   = ws + ES_OFF;                          // [NY,10] f32
        int* csr_ptr  = (int*)o_sc;
        int* csr_fill = csr_ptr + 16448;
        int* csr_cnt  = csr_ptr + 32832;
        int* csr_row  = csr_ptr + 49216;

        // ---- CSR build ----
        zeroi_k<<<(NYc + 255) / 256, blk, 0, stream>>>(csr_cnt, NYc);
        csr_cnt_k<<<(Ec + 255) / 256, blk, 0, stream>>>(tgtI, csr_cnt);
        csr_scan_k<<<1, blk, 0, stream>>>(csr_cnt, csr_ptr, csr_fill);
        csr_fill_k<<<(Ec + 255) / 256, blk, 0, stream>>>(src, tgtI, tet, csr_fill, csr_row);

        // ---- all weight transposes in ONE launch ----
        {
            WArg a;
            int i = 0;
            auto add = [&](const float* s, long d, int K, int N) {
                a.s[i] = s; a.d[i] = d; a.K[i] = K; a.N[i] = N; ++i;
            };
            add(w1_self, T_W1S, 256, 512);
            for (int z = 0; z < 4; ++z) add(w1_rel + (long)z * 131072, T_W1R + (long)z * 131072, 256, 512);
            add(w1_q, T_W1Q, 512, 512);
            add(w1_k, T_W1K, 512, 512);
            add(w1_v, T_W1V, 512, 512);
            add(w2_self, T_W2S, 512, 512);
            for (int z = 0; z < 4; ++z) add(w2_rel + (long)z * 262144, T_W2R + (long)z * 262144, 512, 512);
            add(w2_init, T_W2I, 256, 512);
            add(w2_q, T_W2Q, 512, 512);
            add(w2_k, T_W2K, 512, 512);
            add(w2_v, T_W2V, 512, 512);
            add(w3_self, T_W3S, 512, 256);
            for (int z = 0; z < 4; ++z) add(w3_rel + (long)z * 131072, T_W3R + (long)z * 131072, 512, 256);
            add(w3_init, T_W3I, 256, 256);
            add(w3_q, T_W3Q, 256, 256);
            add(w3_k, T_W3K, 512, 256);
            add(w3_v, T_W3V, 512, 256);
            add(wz, T_WZ, 256, 128);
            int tot = 0;
            for (int e = 0; e < NWENT; ++e) {
                a.t0[e] = tot;
                tot += (a.N[e] >> 5) * (a.K[e] >> 5);
            }
            a.t0[NWENT] = tot;
            wtrall_k<<<tot, blk, 0, stream>>>(a, wbt);
        }

        // ---- ALL f32->bf16 conversions in ONE launch ----
        {
            CvArg c;
            int i = 0;
            long tot = 0;
            auto add = [&](const float* s, bf16* d, long n8) {
                c.s[i] = s; c.d[i] = d; c.t0[i] = tot; tot += n8; ++i;
            };
            add(x, xb, (long)NXc * Fdim / 8);
            add(embed, embf, 4096);
            add(w1_q, wq1n, 32768);
            add(w1_k, wk1n, 32768);
            add(w2_q, wq2n, 32768);
            add(w2_k, wk2n, 32768);
            c.t0[NCENT] = tot;
            cvall_k<<<(int)((tot + 255) / 256), blk, 0, stream>>>(c);
        }

        // ---- WcT_b[f][i] = sum_o wk_b[f,o] wq_b[i,o]  (both blocks, one launch) ----
        mgemm_k<bf16, EP_BF16><<<dim3(4, 4, 2), blk, 0, stream>>>(
            wk1n, wq1n, nullptr, WcT1, nullptr, nullptr,
            512, 512, 512, 512, 512, 524288, 524288, 262144);

        // ---- xT (per-batch [512][SXc]) once ----
        vtr_k<<<dim3(NXc / 64, Fdim / 64, 1), blk, 0, stream>>>(xb, xT, Fdim, Fdim);

        // ---- x-factored attention for O=512 blocks ----
        auto attn12 = [&](const bf16* WcT, long twv, float* oa, bf16* amir) {
            mgemm_k<bf16, EP_BF16><<<dim3(4, 128, 1), blk, 0, stream>>>(
                hbf, WcT, nullptr, qkbuf, nullptr, nullptr,
                NYc, 512, 512, 512, 512, 0, 0, 0);
            mgemm_k<bf16, EP_BF16><<<dim3(8, 4, Bn), blk, 0, stream>>>(
                qkbuf, xb, nullptr, scbf, nullptr, nullptr,
                SYc, SXc, 512, 512, Fdim,
                (long)SYc * 512, (long)SXc * Fdim, (long)SYc * SXc);
            const float sc = 1.f / sqrtf(512.f);
            softmax3_k<<<NYc / 4, blk, 0, stream>>>(scbf, oa, amir, sc);
            mgemm_k<bf16, EP_BF16><<<dim3(4, 4, Bn), blk, 0, stream>>>(
                amir, xT, nullptr, abuf, nullptr, nullptr,
                SYc, Fdim, SXc, SXc, SXc,
                (long)SYc * SXc, 512L * SXc, (long)SYc * Fdim);
            mgemm_k<bf16, EP_RELUB><<<dim3(4, 128, 1), blk, 0, stream>>>(
                abuf, wbt + twv, nullptr, ybuf, (const float*)hbf, nullptr,
                NYc, 512, 512, 512, 512, 0, 0, 0);
        };

        // ---- block 1 ----
        mgemm_k<bf16, EP_BF16><<<dim3(20, 1, 1), blk, 0, stream>>>(
            embf, wbt + T_W1S, nullptr, Z5, nullptr, nullptr,
            128, 2560, INdim, INdim, INdim, 0, 0, 0);
        gather_k<<<(NYc << 6) / 256, blk, 0, stream>>>(
            Z5, csr_ptr, csr_row, nullptr, nullptr, tgt_y, hbf, 512, 6);
        attn12(WcT1, T_W1V, o_a1, (bf16*)o_a2);

        // ---- block 2 ----
        mgemm_k<bf16, EP_BF16><<<dim3(20, 128, 1), blk, 0, stream>>>(
            ybuf, wbt + T_W2S, nullptr, Z5, nullptr, nullptr,
            NYc, 2560, Hdim, Hdim, Hdim, 0, 0, 0);
        mgemm_k<bf16, EP_BF16><<<dim3(4, 1, 1), blk, 0, stream>>>(
            embf, wbt + T_W2I, nullptr, ibuf, nullptr, nullptr,
            128, 512, INdim, INdim, INdim, 0, 0, 0);
        gather_k<<<(NYc << 6) / 256, blk, 0, stream>>>(
            Z5, csr_ptr, csr_row, ibuf, tgt_y, nullptr, hbf, 512, 6);
        attn12(WcT1 + 262144, T_W2V, o_a2, (bf16*)o_a3);

        // ---- block 3 (direct path, O=256) ----
        mgemm_k<bf16, EP_BF16><<<dim3(10, 128, 1), blk, 0, stream>>>(
            ybuf, wbt + T_W3S, nullptr, Z5, nullptr, nullptr,
            NYc, 1280, Hdim, Hdim, Hdim, 0, 0, 0);
        mgemm_k<bf16, EP_BF16><<<dim3(2, 1, 1), blk, 0, stream>>>(
            embf, wbt + T_W3I, nullptr, ibuf, nullptr, nullptr,
            128, 256, INdim, INdim, INdim, 0, 0, 0);
        gather_k<<<(NYc << 5) / 256, blk, 0, stream>>>(
            Z5, csr_ptr, csr_row, ibuf, tgt_y, nullptr, hbf, 256, 5);
        {
            const int O = 256;
            mgemm_k<bf16, EP_BF16><<<dim3(O / 128, 128, 1), blk, 0, stream>>>(
                hbf, wbt + T_W3Q, nullptr, qbuf, nullptr, nullptr,
                NYc, O, O, O, O, 0, 0, 0);
            mgemm_k<bf16, EP_BF16><<<dim3(O / 128, 256, 1), blk, 0, stream>>>(
                xb, wbt + T_W3K, nullptr, abuf, nullptr, nullptr,
                NXc, O, Fdim, Fdim, Fdim, 0, 0, 0);
            mgemm_k<bf16, EP_BF16><<<dim3(256, O / 128, 1), blk, 0, stream>>>(
                wbt + T_W3V, xb, nullptr, ybuf, nullptr, nullptr,
                O, NXc, Fdim, Fdim, Fdim, 0, 0, 0);
            mgemm_k<bf16, EP_BF16><<<dim3(8, 4, Bn), blk, 0, stream>>>(
                qbuf, abuf, nullptr, scbf, nullptr, nullptr,
                SYc, SXc, O, O, O,
                (long)SYc * O, (long)SXc * O, (long)SYc * SXc);
            const float sc = 1.f / sqrtf((float)O);
            softmax3_k<<<NYc / 4, blk, 0, stream>>>(scbf, o_a3, abuf, sc);
            mgemm_k<bf16, EP_RELUB><<<dim3(O / 128, 4, Bn), blk, 0, stream>>>(
                abuf, ybuf, o_y, y3buf, (const float*)hbf, nullptr,
                SYc, O, SXc, SXc, NXc,
                (long)SYc * SXc, (long)SXc, (long)SYc * O);
        }

        // ---- final scores (overwrites CSR scratch) + edge scores ----
        mgemm_k<bf16, EP_BIAS><<<dim3(1, 128, 1), blk, 0, stream>>>(
            y3buf, wbt + T_WZ, o_sc, nullptr, nullptr, bz,
            NYc, Vdim, EMBdim, EMBdim, EMBdim, 0, 0, 0);
        node_k<<<NYc / 4, blk, 0, stream>>>(y3buf, wg, ES);
        easm_k<<<(Ec * 5 + 255) / 256, blk, 0, stream>>>(ES, src, tgtI, bg, o_ers);
    } else {
        // ================= FALLBACK (fp32 FMA) =================
        bf16* y_init = (bf16*)o_y;
        embed_k<<<(NYc * 64 + 255) / 256, blk, 0, stream>>>(embed, tgt_y, y_init, NYc * 64);
        bf16* hbuf = (bf16*)ws;
        bf16* ybuf = (bf16*)(ws + 4194304);
        bf16* qc   = (bf16*)(ws + 8388608);
        bf16* kc   = (bf16*)(ws + 8912896);
        bf16* vc   = (bf16*)(ws + 9961472);
        float* ctxc = ws + 11010048;
        float* agg = o_a3;

        auto h_part = [&](const bf16* yin, int Din, const float* wself, const float* wrel,
                          const float* winit, int O) {
            gemm_k<bf16, float, bf16, false, false, false>
                <<<dim3(O / 128, 128, 1), blk, 0, stream>>>(yin, wself, hbuf, nullptr,
                                                            NYc, O, Din, 0, 0, 0);
            const int sh = (Din == 256) ? 6 : 7;
            for (int r = 0; r < 4; ++r) {
                zero_k<<<2048, blk, 0, stream>>>(agg, (long)NYc * Din / 4);
                scatter_k<<<((Ec << sh) + 255) / 256, blk, 0, stream>>>(yin, src, tgtI, tet,
                                                                        agg, Ec, sh, r);
                gemm_k<float, float, bf16, false, true, false>
                    <<<dim3(O / 128, 128, 1), blk, 0, stream>>>(agg, wrel + (long)r * Din * O,
                                                                hbuf, nullptr, NYc, O, Din, 0, 0, 0);
            }
            if (winit)
                gemm_k<bf16, float, bf16, false, true, false>
                    <<<dim3(O / 128, 128, 1), blk, 0, stream>>>(y_init, winit, hbuf, nullptr,
                                                                NYc, O, INdim, 0, 0, 0);
        };

        auto attn_relu = [&](const float* wq, const float* wk, const float* wv, int O,
                             float* aout, bf16* yb, float* oy) {
            const float sc = 1.f / sqrtf((float)O);
            for (int c = 0; c < NCHUNK; ++c) {
                const bf16* hc = hbuf + (long)c * YRc * O;
                const float* xc = x + (long)c * XRc * Fdim;
                float* ac = aout + (long)c * YRc * SXc;
                gemm_k<bf16, float, bf16, false, false, false>
                    <<<dim3(O / 128, YRc / 128, 1), blk, 0, stream>>>(hc, wq, qc, nullptr,
                                                                      YRc, O, O, 0, 0, 0);
                gemm_k<float, float, bf16, false, false, false>
                    <<<dim3(O / 128, XRc / 128, 1), blk, 0, stream>>>(xc, wk, kc, nullptr,
                                                                      XRc, O, Fdim, 0, 0, 0);
                gemm_k<float, float, bf16, false, false, false>
                    <<<dim3(O / 128, XRc / 128, 1), blk, 0, stream>>>(xc, wv, vc, nullptr,
                                                                      XRc, O, Fdim, 0, 0, 0);
                gemm_k<bf16, bf16, float, true, false, false>
                    <<<dim3(8, 4, CBc), blk, 0, stream>>>(qc, kc, ac, nullptr, SYc, SXc, O,
                                                          (long)SYc * O, (long)SXc * O,
                                                          (long)SYc * SXc);
                softmax2_k<<<YRc, blk, 0, stream>>>(ac, nullptr, sc);
                gemm_k<float, bf16, float, false, false, false>
                    <<<dim3(O / 128, 4, CBc), blk, 0, stream>>>(ac, vc, ctxc, nullptr, SYc, O,
                                                                SXc, (long)SYc * SXc,
                                                                (long)SXc * O, (long)SYc * O);
                long n = (long)YRc * O;
                relu_add_k<<<(int)((n + 255) / 256), blk, 0, stream>>>(
                    hc, ctxc, yb + (long)c * YRc * O, oy ? oy + (long)c * YRc * O : nullptr, n);
            }
        };

        h_part(y_init, 256, w1_self, w1_rel, nullptr, 512);
        attn_relu(w1_q, w1_k, w1_v, 512, o_a1, ybuf, nullptr);
        h_part(ybuf, 512, w2_self, w2_rel, w2_init, 512);
        attn_relu(w2_q, w2_k, w2_v, 512, o_a2, ybuf, nullptr);
        h_part(ybuf, 512, w3_self, w3_rel, w3_init, 256);
        attn_relu(w3_q, w3_k, w3_v, 256, o_a3, ybuf, o_y);

        gemm_k<bf16, float, float, false, false, true>
            <<<dim3(1, 128, 1), blk, 0, stream>>>(ybuf, wz, o_sc, bz, NYc, Vdim, EMBdim, 0, 0, 0);
        edge_k<<<(Ec * 5 + 255) / 256, blk, 0, stream>>>(ybuf, src, tgtI, wg, bg, o_ers, Ec);
    }

    // ---- int passthroughs (one launch) ----
    pass_k<<<(NYc + 3 * Ec + 255) / 256, blk, 0, stream>>>(tyb, tei, tet, out);
}

// Round 22
// 709.194 us; speedup vs baseline: 1.0927x; 1.0864x over previous
//
#include <hip/hip_runtime.h>
#include <hip/hip_bf16.h>
#include <cmath>

// ---------------- constants ----------------
#define Bn     32
#define SYc    512
#define SXc    1024
#define Fdim   512
#define INdim  256
#define Hdim   512
#define EMBdim 256
#define Vdim   128
#define NYc    16384
#define NXc    32768
#define Ec     49152
#define CBc    4
#define NCHUNK (Bn / CBc)
#define YRc    (CBc * SYc)
#define XRc    (CBc * SXc)

typedef float f4v __attribute__((ext_vector_type(4)));
typedef short s8v __attribute__((ext_vector_type(8)));
typedef short s4v __attribute__((ext_vector_type(4)));
typedef __hip_bfloat16 bf16;

__device__ __forceinline__ float ldf(const float* p) { return *p; }
__device__ __forceinline__ float ldf(const bf16* p) { return __bfloat162float(*p); }
__device__ __forceinline__ void stf(float* p, float v) { *p = v; }
__device__ __forceinline__ void stf(bf16* p, float v) { *p = __float2bfloat16(v); }
__device__ __forceinline__ short f2b(float x) {
    bf16 h = __float2bfloat16(x);
    return *reinterpret_cast<const short*>(&h);
}
__device__ __forceinline__ float b2f(short s) {
    bf16 h = *reinterpret_cast<const bf16*>(&s);
    return __bfloat162float(h);
}

// async global->LDS, 16B per lane; dst = base + lane*16 (wave-uniform base)
__device__ __forceinline__ void gload16(const void* g, void* l) {
    __builtin_amdgcn_global_load_lds((const __attribute__((address_space(1))) void*)g,
                                     (__attribute__((address_space(3))) void*)l, 16, 0, 0);
}

// ================= MFMA bf16 GEMM (BK=64) =================
// C[M,N](+)= A[M,K] @ B[K,N]; A row-major bf16 (gload) or f32 (reg-staged);
// B given TRANSPOSED as BT[N][K] bf16 with row stride ldB. 128x128 tile,
// BK=64 (32KB LDS), 4 waves. 8-slot XOR swizzle: unit u=row*8+slot,
// slot=(kp+row)&7 where kp = K-chunk (8 bf16). Requires K%64==0.
enum { EP_F32 = 0, EP_F32ACC, EP_BF16, EP_RELUB, EP_BIAS };

template <typename TA, int EP>
__global__ __launch_bounds__(256) void mgemm_k(
    const TA* __restrict__ A, const bf16* __restrict__ BT,
    float* __restrict__ Cf, bf16* __restrict__ Cb,
    const float* __restrict__ H, const float* __restrict__ bias,
    int M, int N, int K, int ldA, int ldB,
    long sA, long sB, long sC)
{
    __shared__ s8v As[1024];
    __shared__ s8v Bs[1024];
    // XCD-aware bijective swizzle (m204)
    const int nwg = gridDim.x * gridDim.y;
    const int flat = blockIdx.y * gridDim.x + blockIdx.x;
    const int qd = nwg >> 3, rm = nwg & 7;
    const int xcd = flat & 7, base = flat >> 3;
    const int wgid = (xcd < rm ? xcd * (qd + 1) : rm * (qd + 1) + (xcd - rm) * qd) + base;
    const int bx = wgid % gridDim.x, by = wgid / gridDim.x;

    const int tid = threadIdx.x;
    const int l = tid & 63, w = tid >> 6;
    const int wr = w >> 1, wc = w & 1;
    const long bm = (long)by * 128, bn = (long)bx * 128;
    const int z = blockIdx.z;
    const TA* Ab = A + (long)z * sA;
    const bf16* Bb = BT + (long)z * sB;
    const int l15 = l & 15, kq = l >> 4;

    f4v acc[4][4];
#pragma unroll
    for (int i = 0; i < 4; ++i)
#pragma unroll
        for (int j = 0; j < 4; ++j) acc[i][j] = f4v{0.f, 0.f, 0.f, 0.f};

    for (int k0 = 0; k0 < K; k0 += 64) {
        if constexpr (sizeof(TA) == 2) {
#pragma unroll
            for (int i = 0; i < 4; ++i) {
                const int u = w * 256 + i * 64 + l;
                const int row = u >> 3, slot = u & 7;
                const int kp = (slot - row) & 7;
                gload16((const bf16*)Ab + (bm + row) * (long)ldA + k0 + kp * 8,
                        &As[w * 256 + i * 64]);
                gload16(Bb + (bn + row) * (long)ldB + k0 + kp * 8,
                        &Bs[w * 256 + i * 64]);
            }
        } else {
#pragma unroll
            for (int j = 0; j < 4; ++j) {
                const int id = tid * 4 + j;
                const int row = id >> 3, kp = id & 7;
                const int slot = (kp + row) & 7;
                const float* ap = (const float*)Ab + (bm + row) * (long)ldA + k0 + kp * 8;
                f4v v0 = *(const f4v*)ap, v1 = *(const f4v*)(ap + 4);
                s8v t;
                t[0] = f2b(v0.x); t[1] = f2b(v0.y); t[2] = f2b(v0.z); t[3] = f2b(v0.w);
                t[4] = f2b(v1.x); t[5] = f2b(v1.y); t[6] = f2b(v1.z); t[7] = f2b(v1.w);
                As[row * 8 + slot] = t;
            }
#pragma unroll
            for (int i = 0; i < 4; ++i) {
                const int u = w * 256 + i * 64 + l;
                const int row = u >> 3, slot = u & 7;
                const int kp = (slot - row) & 7;
                gload16(Bb + (bn + row) * (long)ldB + k0 + kp * 8,
                        &Bs[w * 256 + i * 64]);
            }
        }
        __syncthreads();
#pragma unroll
        for (int ks = 0; ks < 2; ++ks) {
            s8v af[4], bfr[4];
#pragma unroll
            for (int f = 0; f < 4; ++f) {
                const int ar = wr * 64 + f * 16 + l15;
                af[f] = As[ar * 8 + ((ks * 4 + kq + ar) & 7)];
                const int br = wc * 64 + f * 16 + l15;
                bfr[f] = Bs[br * 8 + ((ks * 4 + kq + br) & 7)];
            }
#pragma unroll
            for (int i = 0; i < 4; ++i)
#pragma unroll
                for (int j = 0; j < 4; ++j)
                    acc[i][j] = __builtin_amdgcn_mfma_f32_16x16x32_bf16(af[i], bfr[j], acc[i][j], 0, 0, 0);
        }
        __syncthreads();
    }

#pragma unroll
    for (int i = 0; i < 4; ++i)
#pragma unroll
        for (int j = 0; j < 4; ++j)
#pragma unroll
            for (int r = 0; r < 4; ++r) {
                const long row = bm + wr * 64 + i * 16 + kq * 4 + r;
                const long col = bn + wc * 64 + j * 16 + l15;
                const long idx = (long)z * sC + row * N + col;
                float v = acc[i][j][r];
                if constexpr (EP == EP_F32) Cf[idx] = v;
                else if constexpr (EP == EP_F32ACC) Cf[idx] += v;
                else if constexpr (EP == EP_BF16) Cb[idx] = __float2bfloat16(v);
                else if constexpr (EP == EP_BIAS) Cf[idx] = v + bias[col];
                else {  // EP_RELUB
                    v += __bfloat162float(((const bf16*)H)[idx]);
                    v = fmaxf(v, 0.f);
                    Cb[idx] = __float2bfloat16(v);
                    if (Cf) Cf[idx] = v;
                }
            }
}

// ================= batched weight transpose (ALL weights, one launch) ==========
#define NWENT 27
struct WArg {
    const float* s[NWENT];
    long d[NWENT];
    int K[NWENT], N[NWENT];
    int t0[NWENT + 1];
};

__global__ __launch_bounds__(256) void wtrall_k(WArg a, bf16* __restrict__ wbt)
{
    __shared__ float T[32][33];
    int b = blockIdx.x;
    int e = 0;
    while (b >= a.t0[e + 1]) ++e;
    const int lt = b - a.t0[e];
    const int K = a.K[e], N = a.N[e];
    const int tx = N >> 5;
    const int n0 = (lt % tx) * 32, k0 = (lt / tx) * 32;
    const float* src = a.s[e];
    bf16* dst = wbt + a.d[e];
    const int t = threadIdx.x;
    const int kr = t >> 3, nc = (t & 7) * 4;
    f4v v = *(const f4v*)(src + (long)(k0 + kr) * N + n0 + nc);
    T[kr][nc] = v.x; T[kr][nc + 1] = v.y; T[kr][nc + 2] = v.z; T[kr][nc + 3] = v.w;
    __syncthreads();
    const int nr = t >> 3, kc = (t & 7) * 4;
    bf16* dp = dst + (long)(n0 + nr) * K + k0 + kc;
    dp[0] = __float2bfloat16(T[kc][nr]);
    dp[1] = __float2bfloat16(T[kc + 1][nr]);
    dp[2] = __float2bfloat16(T[kc + 2][nr]);
    dp[3] = __float2bfloat16(T[kc + 3][nr]);
}

// ================= batched f32->bf16 convert (6 tensors, one launch) ==========
#define NCENT 6
struct CvArg {
    const float* s[NCENT];
    bf16* d[NCENT];
    long t0[NCENT + 1];   // prefix in 8-elem groups
};

__global__ void cvall_k(CvArg a)
{
    long idx = (long)blockIdx.x * blockDim.x + threadIdx.x;
    if (idx >= a.t0[NCENT]) return;
    int e = 0;
    while (idx >= a.t0[e + 1]) ++e;
    const long g = idx - a.t0[e];
    const f4v v0 = ((const f4v*)a.s[e])[g * 2], v1 = ((const f4v*)a.s[e])[g * 2 + 1];
    s8v t;
    t[0] = f2b(v0.x); t[1] = f2b(v0.y); t[2] = f2b(v0.z); t[3] = f2b(v0.w);
    t[4] = f2b(v1.x); t[5] = f2b(v1.y); t[6] = f2b(v1.z); t[7] = f2b(v1.w);
    ((s8v*)a.d[e])[g] = t;
}

// v transpose: bf16 [NXc][ldIn] (cols [0,C)) -> per-batch [C][SXc]
__global__ __launch_bounds__(256) void vtr_k(const bf16* __restrict__ in,
                                             bf16* __restrict__ outp, int C, int ldIn)
{
    __shared__ short T[64][72];
    const int r0 = blockIdx.x * 64, c0 = blockIdx.y * 64;
    const int t = threadIdx.x;
    const int rr = t >> 2, cc = (t & 3) * 16;
    const bf16* ip = in + (long)(r0 + rr) * ldIn + c0 + cc;
    *(s8v*)&T[rr][cc] = *(const s8v*)ip;
    *(s8v*)&T[rr][cc + 8] = *(const s8v*)(ip + 8);
    __syncthreads();
    const int cr = t >> 2, rs = (t & 3) * 16;
    const int b = r0 >> 10, s0 = r0 & 1023;
    bf16* dp = outp + ((long)b * C + (c0 + cr)) * SXc + s0 + rs;
    s8v o0, o1;
#pragma unroll
    for (int i = 0; i < 8; ++i) { o0[i] = T[rs + i][cr]; o1[i] = T[rs + 8 + i][cr]; }
    *(s8v*)dp = o0;
    *(s8v*)(dp + 8) = o1;
}

// ================= CSR build =================
__global__ void zeroi_k(int* __restrict__ p, int n)
{
    int i = blockIdx.x * blockDim.x + threadIdx.x;
    if (i < n) p[i] = 0;
}

__global__ void csr_cnt_k(const int* __restrict__ tgt, int* __restrict__ cnt)
{
    int e = blockIdx.x * blockDim.x + threadIdx.x;
    if (e < Ec) atomicAdd(&cnt[tgt[e] & (NYc - 1)], 1);
}

__global__ __launch_bounds__(256) void csr_scan_k(const int* __restrict__ cnt,
                                                  int* __restrict__ ptr,
                                                  int* __restrict__ pfill)
{
    __shared__ int ps[256];
    const int t = threadIdx.x;
    const int base = t * 64;
    int sum = 0;
    for (int i = 0; i < 64; ++i) sum += cnt[base + i];
    ps[t] = sum;
    __syncthreads();
    for (int off = 1; off < 256; off <<= 1) {
        int v = (t >= off) ? ps[t - off] : 0;
        __syncthreads();
        ps[t] += v;
        __syncthreads();
    }
    int run = (t == 0) ? 0 : ps[t - 1];
    for (int i = 0; i < 64; ++i) {
        ptr[base + i] = run;
        pfill[base + i] = run;
        run += cnt[base + i];
    }
    if (t == 255) ptr[NYc] = run;
}

__global__ void csr_fill_k(const int* __restrict__ src, const int* __restrict__ tgt,
                           const int* __restrict__ et, int* __restrict__ pfill,
                           int* __restrict__ srcrow)
{
    int e = blockIdx.x * blockDim.x + threadIdx.x;
    if (e >= Ec) return;
    int t = tgt[e] & (NYc - 1);
    int pos = atomicAdd(&pfill[t], 1);
    srcrow[pos] = ((src[e] & (NYc - 1)) << 2) | (et[e] & 3);
}

// h(bf16) = Z5.self[zrow(t)] + sum_{edges->t} Z5.rel[et][zrow(src)] (+ ib[irow(t)]).
__global__ __launch_bounds__(256) void gather_k(const bf16* __restrict__ Z5,
                                                const int* __restrict__ ptr,
                                                const int* __restrict__ srcrow,
                                                const bf16* __restrict__ ib,
                                                const int* __restrict__ imap,
                                                const int* __restrict__ zmap,
                                                bf16* __restrict__ hbf,
                                                int O, int sh3 /*log2(O/8)*/)
{
    int idx = blockIdx.x * blockDim.x + threadIdx.x;
    int t = idx >> sh3;
    int c8 = (idx & ((1 << sh3) - 1)) * 8;
    const long fiveO = 5L * O;
    float s[8];
    {
        const int zt = zmap ? (zmap[t] & (Vdim - 1)) : t;
        const s8v v = *(const s8v*)(Z5 + (long)zt * fiveO + c8);
#pragma unroll
        for (int j = 0; j < 8; ++j) s[j] = b2f(v[j]);
    }
    if (ib) {
        const int it = imap ? (imap[t] & (Vdim - 1)) : t;
        const s8v v = *(const s8v*)(ib + (long)it * O + c8);
#pragma unroll
        for (int j = 0; j < 8; ++j) s[j] += b2f(v[j]);
    }
    const int beg = ptr[t], end = ptr[t + 1];
    for (int i = beg; i < end; ++i) {
        const int sr = srcrow[i];
        int srow = sr >> 2;
        const int et = sr & 3;
        if (zmap) srow = zmap[srow] & (Vdim - 1);
        const s8v v = *(const s8v*)(Z5 + (long)srow * fiveO + (long)(1 + et) * O + c8);
#pragma unroll
        for (int j = 0; j < 8; ++j) s[j] += b2f(v[j]);
    }
    s8v hv;
#pragma unroll
    for (int j = 0; j < 8; ++j) hv[j] = f2b(s[j]);
    *(s8v*)(hbf + (long)t * O + c8) = hv;
}

// ================= shared small kernels =================
__global__ void embed_k(const float* __restrict__ embed, const int* __restrict__ ids,
                        bf16* __restrict__ y, int n)
{
    int idx = blockIdx.x * blockDim.x + threadIdx.x;
    if (idx >= n) return;
    int row = idx >> 6, q = idx & 63;
    int id = ids[row] & (Vdim - 1);
    f4v v = ((const f4v*)embed)[(long)id * 64 + q];
    bf16* yp = y + (long)row * 256 + q * 4;
    yp[0] = __float2bfloat16(v.x); yp[1] = __float2bfloat16(v.y);
    yp[2] = __float2bfloat16(v.z); yp[3] = __float2bfloat16(v.w);
}

// legacy scatter (fallback path)
__global__ void scatter_k(const bf16* __restrict__ y, const int* __restrict__ src,
                          const int* __restrict__ tgt, const int* __restrict__ et,
                          float* __restrict__ agg, int E, int sh, int r)
{
    int idx = blockIdx.x * blockDim.x + threadIdx.x;
    if (idx >= (E << sh)) return;
    int e = idx >> sh;
    if ((et[e] & 3) != r) return;
    int c = (idx & ((1 << sh) - 1)) * 4;
    int D = 4 << sh;
    int s = src[e] & (NYc - 1);
    int t = tgt[e] & (NYc - 1);
    const bf16* yp = y + (long)s * D + c;
    float* ap = agg + (long)t * D + c;
    atomicAdd(ap + 0, __bfloat162float(yp[0]));
    atomicAdd(ap + 1, __bfloat162float(yp[1]));
    atomicAdd(ap + 2, __bfloat162float(yp[2]));
    atomicAdd(ap + 3, __bfloat162float(yp[3]));
}

__global__ void zero_k(float* __restrict__ p, long n4)
{
    long i = (long)blockIdx.x * blockDim.x + threadIdx.x;
    const long stride = (long)gridDim.x * blockDim.x;
    for (; i < n4; i += stride) ((f4v*)p)[i] = f4v{0.f, 0.f, 0.f, 0.f};
}

// softmax: wave-per-row; bf16 scores -> f32 alpha + bf16 mirror
__global__ __launch_bounds__(256) void softmax3_k(const bf16* __restrict__ sin,
                                                  float* __restrict__ aout,
                                                  bf16* __restrict__ amir, float scale)
{
    const int wid = threadIdx.x >> 6;
    const int l = threadIdx.x & 63;
    const long row = (long)blockIdx.x * 4 + wid;
    const bf16* sp = sin + row * SXc + l * 16;
    float v[16];
    {
        const s8v a0 = *(const s8v*)sp;
        const s8v a1 = *(const s8v*)(sp + 8);
#pragma unroll
        for (int i = 0; i < 8; ++i) { v[i] = b2f(a0[i]) * scale; v[8 + i] = b2f(a1[i]) * scale; }
    }
    float m = v[0];
#pragma unroll
    for (int i = 1; i < 16; ++i) m = fmaxf(m, v[i]);
    for (int off = 32; off > 0; off >>= 1) m = fmaxf(m, __shfl_xor(m, off));
    float sum = 0.f;
#pragma unroll
    for (int i = 0; i < 16; ++i) { v[i] = __expf(v[i] - m); sum += v[i]; }
    for (int off = 32; off > 0; off >>= 1) sum += __shfl_xor(sum, off);
    const float inv = 1.0f / sum;
    float* ap = aout + row * SXc + l * 16;
    bf16* mp = amir + row * SXc + l * 16;
    f4v o0, o1, o2, o3;
    s8v m0, m1;
#pragma unroll
    for (int i = 0; i < 4; ++i) {
        o0[i] = v[i] * inv; o1[i] = v[4 + i] * inv;
        o2[i] = v[8 + i] * inv; o3[i] = v[12 + i] * inv;
    }
#pragma unroll
    for (int i = 0; i < 8; ++i) { m0[i] = f2b(v[i] * inv); m1[i] = f2b(v[8 + i] * inv); }
    ((f4v*)ap)[0] = o0; ((f4v*)ap)[1] = o1; ((f4v*)ap)[2] = o2; ((f4v*)ap)[3] = o3;
    *(s8v*)mp = m0; *(s8v*)(mp + 8) = m1;
}

// softmax in-place f32 (fallback path)
__global__ __launch_bounds__(256) void softmax2_k(float* __restrict__ s,
                                                  bf16* __restrict__ ab, float scale)
{
    __shared__ float red[256];
    float* sp = s + (long)blockIdx.x * SXc;
    const int tid = threadIdx.x;
    float v[4];
#pragma unroll
    for (int i = 0; i < 4; ++i) v[i] = sp[tid + 256 * i] * scale;
    float m = fmaxf(fmaxf(v[0], v[1]), fmaxf(v[2], v[3]));
    red[tid] = m; __syncthreads();
    for (int off = 128; off > 0; off >>= 1) {
        if (tid < off) red[tid] = fmaxf(red[tid], red[tid + off]);
        __syncthreads();
    }
    m = red[0]; __syncthreads();
    float e[4], sum = 0.f;
#pragma unroll
    for (int i = 0; i < 4; ++i) { e[i] = __expf(v[i] - m); sum += e[i]; }
    red[tid] = sum; __syncthreads();
    for (int off = 128; off > 0; off >>= 1) {
        if (tid < off) red[tid] += red[tid + off];
        __syncthreads();
    }
    const float inv = 1.0f / red[0];
#pragma unroll
    for (int i = 0; i < 4; ++i) {
        float a = e[i] * inv;
        sp[tid + 256 * i] = a;
        if (ab) ab[(long)blockIdx.x * SXc + tid + 256 * i] = __float2bfloat16(a);
    }
}

__global__ void relu_add_k(const bf16* __restrict__ h, const float* __restrict__ c,
                           bf16* __restrict__ y, float* __restrict__ out, long n)
{
    long i = (long)blockIdx.x * blockDim.x + threadIdx.x;
    if (i >= n) return;
    float v = __bfloat162float(h[i]) + c[i];
    v = v > 0.f ? v : 0.f;
    y[i] = __float2bfloat16(v);
    if (out) out[i] = v;
}

// all 3 int passthroughs in one launch
__global__ void pass_k(const int* __restrict__ tyb, const int* __restrict__ tei,
                       const int* __restrict__ tet, float* __restrict__ out)
{
    int i = blockIdx.x * blockDim.x + threadIdx.x;
    if (i < NYc) out[4194304 + i] = (float)tyb[i];
    else if (i < NYc + 2 * Ec) out[4210688 + (i - NYc)] = (float)tei[i - NYc];
    else if (i < NYc + 3 * Ec) out[4308992 + (i - NYc - 2 * Ec)] = (float)tet[i - NYc - 2 * Ec];
}

// per-node edge projection: ES[n][j]   = y3[n] . wg_top[:,j]   (j<5)
//                           ES[n][5+j] = y3[n] . wg_bot[:,j]
__global__ __launch_bounds__(256) void node_k(const bf16* __restrict__ y,
                                              const float* __restrict__ wg,
                                              float* __restrict__ ES)
{
    __shared__ float wgs[2560];
    for (int i = threadIdx.x; i < 2560; i += 256) wgs[i] = wg[i];
    __syncthreads();
    const int wid = threadIdx.x >> 6, l = threadIdx.x & 63;
    const int row = blockIdx.x * 4 + wid;
    const s4v yv = *(const s4v*)(y + (long)row * EMBdim + l * 4);
    float acc[10] = {0.f, 0.f, 0.f, 0.f, 0.f, 0.f, 0.f, 0.f, 0.f, 0.f};
#pragma unroll
    for (int c = 0; c < 4; ++c) {
        const float v = b2f(yv[c]);
        const float* wt = &wgs[(l * 4 + c) * 5];
        const float* wb = &wgs[(EMBdim + l * 4 + c) * 5];
#pragma unroll
        for (int j = 0; j < 5; ++j) {
            acc[j] = fmaf(v, wt[j], acc[j]);
            acc[5 + j] = fmaf(v, wb[j], acc[5 + j]);
        }
    }
#pragma unroll
    for (int j = 0; j < 10; ++j)
        for (int off = 32; off > 0; off >>= 1) acc[j] += __shfl_xor(acc[j], off);
    float* ep = ES + (long)row * 10;
#pragma unroll
    for (int j = 0; j < 10; ++j)
        if (l == j) ep[j] = acc[j];
}

// edge assembly: out[e][j] = ES[src][j] + ES[tgt][5+j] + bg[j]
__global__ void easm_k(const float* __restrict__ ES, const int* __restrict__ src,
                       const int* __restrict__ tgt, const float* __restrict__ bg,
                       float* __restrict__ out)
{
    int idx = blockIdx.x * blockDim.x + threadIdx.x;
    if (idx >= Ec * 5) return;
    int e = idx / 5, j = idx - e * 5;
    int s = src[e] & (NYc - 1), t = tgt[e] & (NYc - 1);
    out[idx] = ES[(long)s * 10 + j] + ES[(long)t * 10 + 5 + j] + bg[j];
}

// legacy edge (fallback path)
__global__ void edge_k(const bf16* __restrict__ y, const int* __restrict__ src,
                       const int* __restrict__ tgt, const float* __restrict__ wg,
                       const float* __restrict__ bg, float* __restrict__ out, int E)
{
    int idx = blockIdx.x * blockDim.x + threadIdx.x;
    if (idx >= E * 5) return;
    int e = idx / 5, j = idx - e * 5;
    int s = src[e] & (NYc - 1), t = tgt[e] & (NYc - 1);
    const bf16* ys = y + (long)s * EMBdim;
    const bf16* yt = y + (long)t * EMBdim;
    float acc = bg[j];
    for (int c = 0; c < EMBdim; ++c) acc = fmaf(__bfloat162float(ys[c]), wg[c * 5 + j], acc);
    for (int c = 0; c < EMBdim; ++c) acc = fmaf(__bfloat162float(yt[c]), wg[(EMBdim + c) * 5 + j], acc);
    out[idx] = acc;
}

// ================= fallback fp32 GEMM (known-good) =================
template <typename TA, typename TB, typename TC, bool TRANSB, bool ACC, bool BIAS>
__global__ __launch_bounds__(256) void gemm_k(
    const TA* __restrict__ A, const TB* __restrict__ B, TC* __restrict__ C,
    const float* __restrict__ bias, int M, int N, int K,
    long sA, long sB, long sC)
{
    A += (long)blockIdx.z * sA;
    B += (long)blockIdx.z * sB;
    C += (long)blockIdx.z * sC;
    __shared__ float As[8][128];
    __shared__ float Bs[8][132];
    const int tid = threadIdx.x;
    const int bm = blockIdx.y * 128;
    const int bn = blockIdx.x * 128;
    const int tx = tid & 15;
    const int ty = tid >> 4;
    float acc[8][8];
#pragma unroll
    for (int i = 0; i < 8; ++i)
#pragma unroll
        for (int j = 0; j < 8; ++j) acc[i][j] = 0.f;
    const int ar = tid >> 1;
    const int ac = (tid & 1) * 4;
    for (int k0 = 0; k0 < K; k0 += 8) {
        {
            const TA* ap = A + (long)(bm + ar) * K + (k0 + ac);
            float a0 = ldf(ap + 0), a1 = ldf(ap + 1), a2 = ldf(ap + 2), a3 = ldf(ap + 3);
            As[ac + 0][ar] = a0; As[ac + 1][ar] = a1;
            As[ac + 2][ar] = a2; As[ac + 3][ar] = a3;
        }
        if (!TRANSB) {
            const int bk = tid >> 5, bc = (tid & 31) * 4;
            const TB* bp = B + (long)(k0 + bk) * N + (bn + bc);
            Bs[bk][bc + 0] = ldf(bp + 0); Bs[bk][bc + 1] = ldf(bp + 1);
            Bs[bk][bc + 2] = ldf(bp + 2); Bs[bk][bc + 3] = ldf(bp + 3);
        } else {
            const int bn2 = tid >> 1, bc = (tid & 1) * 4;
            const TB* bp = B + (long)(bn + bn2) * K + (k0 + bc);
            Bs[bc + 0][bn2] = ldf(bp + 0); Bs[bc + 1][bn2] = ldf(bp + 1);
            Bs[bc + 2][bn2] = ldf(bp + 2); Bs[bc + 3][bn2] = ldf(bp + 3);
        }
        __syncthreads();
#pragma unroll
        for (int kk = 0; kk < 8; ++kk) {
            float a[8], b[8];
            *(f4v*)&a[0] = *(const f4v*)&As[kk][ty * 8];
            *(f4v*)&a[4] = *(const f4v*)&As[kk][ty * 8 + 4];
            *(f4v*)&b[0] = *(const f4v*)&Bs[kk][tx * 8];
            *(f4v*)&b[4] = *(const f4v*)&Bs[kk][tx * 8 + 4];
#pragma unroll
            for (int i = 0; i < 8; ++i)
#pragma unroll
                for (int j = 0; j < 8; ++j)
                    acc[i][j] = fmaf(a[i], b[j], acc[i][j]);
        }
        __syncthreads();
    }
#pragma unroll
    for (int i = 0; i < 8; ++i) {
        const int row = bm + ty * 8 + i;
#pragma unroll
        for (int j = 0; j < 8; ++j) {
            const int col = bn + tx * 8 + j;
            float v = acc[i][j];
            if (BIAS) v += bias[col];
            TC* cp = C + (long)row * N + col;
            if (ACC) v += ldf((const TC*)cp);
            stf(cp, v);
        }
    }
}

// ================= entry =================
#define T_W1S 0L
#define T_W1R 131072L
#define T_W1Q 655360L
#define T_W1K 917504L
#define T_W1V 1179648L
#define T_W2S 1441792L
#define T_W2R 1703936L
#define T_W2I 2752512L
#define T_W2Q 2883584L
#define T_W2K 3145728L
#define T_W2V 3407872L
#define T_W3S 3670016L
#define T_W3R 3801088L
#define T_W3I 4325376L
#define T_W3Q 4390912L
#define T_W3K 4456448L
#define T_W3V 4587520L
#define T_WZ  4718592L
#define WQWK_OFF 27541504L
#define XB_OFF   28311552L
#define Z5_OFF   36700160L
#define EMBF_OFF 57671680L
#define XT_OFF   57688064L
#define WCT_OFF  66076672L
#define ES_OFF   66338816L
#define WS_FAST_BYTES 301989888UL   // 288 MiB (evidence: ws poison fill ~870 MiB)

extern "C" void kernel_launch(void* const* d_in, const int* in_sizes, int n_in,
                              void* d_out, int out_size, void* d_ws, size_t ws_size,
                              hipStream_t stream)
{
    const float* x      = (const float*)d_in[0];
    const int*   tgt_y  = (const int*)d_in[2];
    const int*   tei    = (const int*)d_in[3];
    const int*   src    = tei;
    const int*   tgtI   = tei + Ec;
    const int*   tet    = (const int*)d_in[4];
    const int*   tyb    = (const int*)d_in[5];
    const float* embed  = (const float*)d_in[6];
    const float* w1_self = (const float*)d_in[7];
    const float* w1_rel  = (const float*)d_in[8];
    const float* w1_q    = (const float*)d_in[9];
    const float* w1_k    = (const float*)d_in[10];
    const float* w1_v    = (const float*)d_in[11];
    const float* w2_self = (const float*)d_in[12];
    const float* w2_rel  = (const float*)d_in[13];
    const float* w2_init = (const float*)d_in[14];
    const float* w2_q    = (const float*)d_in[15];
    const float* w2_k    = (const float*)d_in[16];
    const float* w2_v    = (const float*)d_in[17];
    const float* w3_self = (const float*)d_in[18];
    const float* w3_rel  = (const float*)d_in[19];
    const float* w3_init = (const float*)d_in[20];
    const float* w3_q    = (const float*)d_in[21];
    const float* w3_k    = (const float*)d_in[22];
    const float* w3_v    = (const float*)d_in[23];
    const float* wz      = (const float*)d_in[24];
    const float* bz      = (const float*)d_in[25];
    const float* wg      = (const float*)d_in[26];
    const float* bg      = (const float*)d_in[27];

    float* out = (float*)d_out;
    float* ws  = (float*)d_ws;

    float* o_y   = out;
    float* o_sc  = out + 4358144;
    float* o_ers = out + 6455296;
    float* o_a1  = out + 6701056;
    float* o_a2  = out + 23478272;
    float* o_a3  = out + 40255488;

    dim3 blk(256);

    if (ws_size >= WS_FAST_BYTES) {
        // ========= FAST PATH (MFMA BK=64, rank-128 y_init, x-factored attn) ======
        bf16* hbf   = (bf16*)ws;
        bf16* ibuf  = (bf16*)(ws + 4194304);
        bf16* abuf  = (bf16*)(ws + 8388608);   // ax (blocks 1/2); k3+amir3 (block 3)
        bf16* ybuf  = (bf16*)(ws + 16777216);  // y; vT3 during attn3
        bf16* qbuf  = (bf16*)(ws + 20971520);  // q3; y3buf upper 8MB
        bf16* y3buf = qbuf + 4194304;
        bf16* wbt   = (bf16*)(ws + 25165824);
        bf16* wq1n  = (bf16*)(ws + WQWK_OFF);              // [512,512] non-transposed
        bf16* wk1n  = wq1n + 262144;
        bf16* wq2n  = wq1n + 524288;
        bf16* wk2n  = wq1n + 786432;
        bf16* xb    = (bf16*)(ws + XB_OFF);
        bf16* Z5    = (bf16*)(ws + Z5_OFF);
        bf16* scbf  = Z5;                                   // [NY,1024] bf16
        bf16* qkbuf = Z5 + 16777216;                        // [NY,512] bf16
        bf16* embf  = (bf16*)(ws + EMBF_OFF);
        bf16* xT    = (bf16*)(ws + XT_OFF);                 // per-batch [512][SXc]
        bf16* WcT1  = (bf16*)(ws + WCT_OFF);                // [512,512]
        float* ES   = ws + ES_OFF;                          // [NY,10] f32
        int* csr_ptr  = (int*)o_sc;
        int* csr_fill = csr_ptr + 16448;
        int* csr_cnt  = csr_ptr + 32832;
        int* csr_row  = csr_ptr + 49216;

        // ---- CSR build ----
        zeroi_k<<<(NYc + 255) / 256, blk, 0, stream>>>(csr_cnt, NYc);
        csr_cnt_k<<<(Ec + 255) / 256, blk, 0, stream>>>(tgtI, csr_cnt);
        csr_scan_k<<<1, blk, 0, stream>>>(csr_cnt, csr_ptr, csr_fill);
        csr_fill_k<<<(Ec + 255) / 256, blk, 0, stream>>>(src, tgtI, tet, csr_fill, csr_row);

        // ---- all weight transposes in ONE launch ----
        {
            WArg a;
            int i = 0;
            auto add = [&](const float* s, long d, int K, int N) {
                a.s[i] = s; a.d[i] = d; a.K[i] = K; a.N[i] = N; ++i;
            };
            add(w1_self, T_W1S, 256, 512);
            for (int z = 0; z < 4; ++z) add(w1_rel + (long)z * 131072, T_W1R + (long)z * 131072, 256, 512);
            add(w1_q, T_W1Q, 512, 512);
            add(w1_k, T_W1K, 512, 512);
            add(w1_v, T_W1V, 512, 512);
            add(w2_self, T_W2S, 512, 512);
            for (int z = 0; z < 4; ++z) add(w2_rel + (long)z * 262144, T_W2R + (long)z * 262144, 512, 512);
            add(w2_init, T_W2I, 256, 512);
            add(w2_q, T_W2Q, 512, 512);
            add(w2_k, T_W2K, 512, 512);
            add(w2_v, T_W2V, 512, 512);
            add(w3_self, T_W3S, 512, 256);
            for (int z = 0; z < 4; ++z) add(w3_rel + (long)z * 131072, T_W3R + (long)z * 131072, 512, 256);
            add(w3_init, T_W3I, 256, 256);
            add(w3_q, T_W3Q, 256, 256);
            add(w3_k, T_W3K, 512, 256);
            add(w3_v, T_W3V, 512, 256);
            add(wz, T_WZ, 256, 128);
            int tot = 0;
            for (int e = 0; e < NWENT; ++e) {
                a.t0[e] = tot;
                tot += (a.N[e] >> 5) * (a.K[e] >> 5);
            }
            a.t0[NWENT] = tot;
            wtrall_k<<<tot, blk, 0, stream>>>(a, wbt);
        }

        // ---- ALL f32->bf16 conversions in ONE launch ----
        {
            CvArg c;
            int i = 0;
            long tot = 0;
            auto add = [&](const float* s, bf16* d, long n8) {
                c.s[i] = s; c.d[i] = d; c.t0[i] = tot; tot += n8; ++i;
            };
            add(x, xb, (long)NXc * Fdim / 8);
            add(embed, embf, 4096);
            add(w1_q, wq1n, 32768);
            add(w1_k, wk1n, 32768);
            add(w2_q, wq2n, 32768);
            add(w2_k, wk2n, 32768);
            c.t0[NCENT] = tot;
            cvall_k<<<(int)((tot + 255) / 256), blk, 0, stream>>>(c);
        }

        // ---- WcT_b[f][i] = sum_o wk_b[f,o] wq_b[i,o]  (both blocks, one launch) ----
        mgemm_k<bf16, EP_BF16><<<dim3(4, 4, 2), blk, 0, stream>>>(
            wk1n, wq1n, nullptr, WcT1, nullptr, nullptr,
            512, 512, 512, 512, 512, 524288, 524288, 262144);

        // ---- xT (per-batch [512][SXc]) once ----
        vtr_k<<<dim3(NXc / 64, Fdim / 64, 1), blk, 0, stream>>>(xb, xT, Fdim, Fdim);

        // ---- x-factored attention for O=512 blocks ----
        auto attn12 = [&](const bf16* WcT, long twv, float* oa, bf16* amir) {
            mgemm_k<bf16, EP_BF16><<<dim3(4, 128, 1), blk, 0, stream>>>(
                hbf, WcT, nullptr, qkbuf, nullptr, nullptr,
                NYc, 512, 512, 512, 512, 0, 0, 0);
            mgemm_k<bf16, EP_BF16><<<dim3(8, 4, Bn), blk, 0, stream>>>(
                qkbuf, xb, nullptr, scbf, nullptr, nullptr,
                SYc, SXc, 512, 512, Fdim,
                (long)SYc * 512, (long)SXc * Fdim, (long)SYc * SXc);
            const float sc = 1.f / sqrtf(512.f);
            softmax3_k<<<NYc / 4, blk, 0, stream>>>(scbf, oa, amir, sc);
            mgemm_k<bf16, EP_BF16><<<dim3(4, 4, Bn), blk, 0, stream>>>(
                amir, xT, nullptr, abuf, nullptr, nullptr,
                SYc, Fdim, SXc, SXc, SXc,
                (long)SYc * SXc, 512L * SXc, (long)SYc * Fdim);
            mgemm_k<bf16, EP_RELUB><<<dim3(4, 128, 1), blk, 0, stream>>>(
                abuf, wbt + twv, nullptr, ybuf, (const float*)hbf, nullptr,
                NYc, 512, 512, 512, 512, 0, 0, 0);
        };

        // ---- block 1 ----
        mgemm_k<bf16, EP_BF16><<<dim3(20, 1, 1), blk, 0, stream>>>(
            embf, wbt + T_W1S, nullptr, Z5, nullptr, nullptr,
            128, 2560, INdim, INdim, INdim, 0, 0, 0);
        gather_k<<<(NYc << 6) / 256, blk, 0, stream>>>(
            Z5, csr_ptr, csr_row, nullptr, nullptr, tgt_y, hbf, 512, 6);
        attn12(WcT1, T_W1V, o_a1, (bf16*)o_a2);

        // ---- block 2 ----
        mgemm_k<bf16, EP_BF16><<<dim3(20, 128, 1), blk, 0, stream>>>(
            ybuf, wbt + T_W2S, nullptr, Z5, nullptr, nullptr,
            NYc, 2560, Hdim, Hdim, Hdim, 0, 0, 0);
        mgemm_k<bf16, EP_BF16><<<dim3(4, 1, 1), blk, 0, stream>>>(
            embf, wbt + T_W2I, nullptr, ibuf, nullptr, nullptr,
            128, 512, INdim, INdim, INdim, 0, 0, 0);
        gather_k<<<(NYc << 6) / 256, blk, 0, stream>>>(
            Z5, csr_ptr, csr_row, ibuf, tgt_y, nullptr, hbf, 512, 6);
        attn12(WcT1 + 262144, T_W2V, o_a2, (bf16*)o_a3);

        // ---- block 3 (direct path, O=256) ----
        mgemm_k<bf16, EP_BF16><<<dim3(10, 128, 1), blk, 0, stream>>>(
            ybuf, wbt + T_W3S, nullptr, Z5, nullptr, nullptr,
            NYc, 1280, Hdim, Hdim, Hdim, 0, 0, 0);
        mgemm_k<bf16, EP_BF16><<<dim3(2, 1, 1), blk, 0, stream>>>(
            embf, wbt + T_W3I, nullptr, ibuf, nullptr, nullptr,
            128, 256, INdim, INdim, INdim, 0, 0, 0);
        gather_k<<<(NYc << 5) / 256, blk, 0, stream>>>(
            Z5, csr_ptr, csr_row, ibuf, tgt_y, nullptr, hbf, 256, 5);
        {
            const int O = 256;
            mgemm_k<bf16, EP_BF16><<<dim3(O / 128, 128, 1), blk, 0, stream>>>(
                hbf, wbt + T_W3Q, nullptr, qbuf, nullptr, nullptr,
                NYc, O, O, O, O, 0, 0, 0);
            mgemm_k<bf16, EP_BF16><<<dim3(O / 128, 256, 1), blk, 0, stream>>>(
                xb, wbt + T_W3K, nullptr, abuf, nullptr, nullptr,
                NXc, O, Fdim, Fdim, Fdim, 0, 0, 0);
            mgemm_k<bf16, EP_BF16><<<dim3(256, O / 128, 1), blk, 0, stream>>>(
                wbt + T_W3V, xb, nullptr, ybuf, nullptr, nullptr,
                O, NXc, Fdim, Fdim, Fdim, 0, 0, 0);
            mgemm_k<bf16, EP_BF16><<<dim3(8, 4, Bn), blk, 0, stream>>>(
                qbuf, abuf, nullptr, scbf, nullptr, nullptr,
                SYc, SXc, O, O, O,
                (long)SYc * O, (long)SXc * O, (long)SYc * SXc);
            const float sc = 1.f / sqrtf((float)O);
            softmax3_k<<<NYc / 4, blk, 0, stream>>>(scbf, o_a3, abuf, sc);
            mgemm_k<bf16, EP_RELUB><<<dim3(O / 128, 4, Bn), blk, 0, stream>>>(
                abuf, ybuf, o_y, y3buf, (const float*)hbf, nullptr,
                SYc, O, SXc, SXc, NXc,
                (long)SYc * SXc, (long)SXc, (long)SYc * O);
        }

        // ---- final scores (overwrites CSR scratch) + edge scores ----
        mgemm_k<bf16, EP_BIAS><<<dim3(1, 128, 1), blk, 0, stream>>>(
            y3buf, wbt + T_WZ, o_sc, nullptr, nullptr, bz,
            NYc, Vdim, EMBdim, EMBdim, EMBdim, 0, 0, 0);
        node_k<<<NYc / 4, blk, 0, stream>>>(y3buf, wg, ES);
        easm_k<<<(Ec * 5 + 255) / 256, blk, 0, stream>>>(ES, src, tgtI, bg, o_ers);
    } else {
        // ================= FALLBACK (fp32 FMA) =================
        bf16* y_init = (bf16*)o_y;
        embed_k<<<(NYc * 64 + 255) / 256, blk, 0, stream>>>(embed, tgt_y, y_init, NYc * 64);
        bf16* hbuf = (bf16*)ws;
        bf16* ybuf = (bf16*)(ws + 4194304);
        bf16* qc   = (bf16*)(ws + 8388608);
        bf16* kc   = (bf16*)(ws + 8912896);
        bf16* vc   = (bf16*)(ws + 9961472);
        float* ctxc = ws + 11010048;
        float* agg = o_a3;

        auto h_part = [&](const bf16* yin, int Din, const float* wself, const float* wrel,
                          const float* winit, int O) {
            gemm_k<bf16, float, bf16, false, false, false>
                <<<dim3(O / 128, 128, 1), blk, 0, stream>>>(yin, wself, hbuf, nullptr,
                                                            NYc, O, Din, 0, 0, 0);
            const int sh = (Din == 256) ? 6 : 7;
            for (int r = 0; r < 4; ++r) {
                zero_k<<<2048, blk, 0, stream>>>(agg, (long)NYc * Din / 4);
                scatter_k<<<((Ec << sh) + 255) / 256, blk, 0, stream>>>(yin, src, tgtI, tet,
                                                                        agg, Ec, sh, r);
                gemm_k<float, float, bf16, false, true, false>
                    <<<dim3(O / 128, 128, 1), blk, 0, stream>>>(agg, wrel + (long)r * Din * O,
                                                                hbuf, nullptr, NYc, O, Din, 0, 0, 0);
            }
            if (winit)
                gemm_k<bf16, float, bf16, false, true, false>
                    <<<dim3(O / 128, 128, 1), blk, 0, stream>>>(y_init, winit, hbuf, nullptr,
                                                                NYc, O, INdim, 0, 0, 0);
        };

        auto attn_relu = [&](const float* wq, const float* wk, const float* wv, int O,
                             float* aout, bf16* yb, float* oy) {
            const float sc = 1.f / sqrtf((float)O);
            for (int c = 0; c < NCHUNK; ++c) {
                const bf16* hc = hbuf + (long)c * YRc * O;
                const float* xc = x + (long)c * XRc * Fdim;
                float* ac = aout + (long)c * YRc * SXc;
                gemm_k<bf16, float, bf16, false, false, false>
                    <<<dim3(O / 128, YRc / 128, 1), blk, 0, stream>>>(hc, wq, qc, nullptr,
                                                                      YRc, O, O, 0, 0, 0);
                gemm_k<float, float, bf16, false, false, false>
                    <<<dim3(O / 128, XRc / 128, 1), blk, 0, stream>>>(xc, wk, kc, nullptr,
                                                                      XRc, O, Fdim, 0, 0, 0);
                gemm_k<float, float, bf16, false, false, false>
                    <<<dim3(O / 128, XRc / 128, 1), blk, 0, stream>>>(xc, wv, vc, nullptr,
                                                                      XRc, O, Fdim, 0, 0, 0);
                gemm_k<bf16, bf16, float, true, false, false>
                    <<<dim3(8, 4, CBc), blk, 0, stream>>>(qc, kc, ac, nullptr, SYc, SXc, O,
                                                          (long)SYc * O, (long)SXc * O,
                                                          (long)SYc * SXc);
                softmax2_k<<<YRc, blk, 0, stream>>>(ac, nullptr, sc);
                gemm_k<float, bf16, float, false, false, false>
                    <<<dim3(O / 128, 4, CBc), blk, 0, stream>>>(ac, vc, ctxc, nullptr, SYc, O,
                                                                SXc, (long)SYc * SXc,
                                                                (long)SXc * O, (long)SYc * O);
                long n = (long)YRc * O;
                relu_add_k<<<(int)((n + 255) / 256), blk, 0, stream>>>(
                    hc, ctxc, yb + (long)c * YRc * O, oy ? oy + (long)c * YRc * O : nullptr, n);
            }
        };

        h_part(y_init, 256, w1_self, w1_rel, nullptr, 512);
        attn_relu(w1_q, w1_k, w1_v, 512, o_a1, ybuf, nullptr);
        h_part(ybuf, 512, w2_self, w2_rel, w2_init, 512);
        attn_relu(w2_q, w2_k, w2_v, 512, o_a2, ybuf, nullptr);
        h_part(ybuf, 512, w3_self, w3_rel, w3_init, 256);
        attn_relu(w3_q, w3_k, w3_v, 256, o_a3, ybuf, o_y);

        gemm_k<bf16, float, float, false, false, true>
            <<<dim3(1, 128, 1), blk, 0, stream>>>(ybuf, wz, o_sc, bz, NYc, Vdim, EMBdim, 0, 0, 0);
        edge_k<<<(Ec * 5 + 255) / 256, blk, 0, stream>>>(ybuf, src, tgtI, wg, bg, o_ers, Ec);
    }

    // ---- int passthroughs (one launch) ----
    pass_k<<<(NYc + 3 * Ec + 255) / 256, blk, 0, stream>>>(tyb, tei, tet, out);
}